// Round 2
// baseline (3996.312 us; speedup 1.0000x reference)
//
#include <hip/hip_runtime.h>

// ---------------------------------------------------------------------------
// NeuronCircuitQKV round 1: routed Householder circuits + causal attention.
// B=2 S=2048 D=R=1024 H=8 DH=128 NI=8 NP=32 NO=8 K=3
// - All 8 big GEMMs (M=4096,N=1024,K=8192) via 2xfp16-split MFMA (3 mfma per
//   product, rel err ~2^-22): outputs feed a top-k router, so must be
//   fp32-faithful.
// - A operand built on the fly inside the GEMM (mixture-weight scale + split),
//   B = pre-transposed split planes in a single reused workspace buffer.
// - Workspace ~101 MB (round 0's 521 MB likely overflowed ws_size -> abort).
// ---------------------------------------------------------------------------

typedef __attribute__((ext_vector_type(4))) float f32x4;
typedef _Float16 f16x8 __attribute__((ext_vector_type(8)));
typedef _Float16 f16x4 __attribute__((ext_vector_type(4)));

static constexpr int S_LEN  = 2048;
static constexpr int TOK    = 4096;   // B*S
static constexpr int DMODEL = 1024;
static constexpr int KDIM   = 8192;   // 8 experts * 1024

__device__ __forceinline__ void async16(const void* g, void* l) {
  __builtin_amdgcn_global_load_lds(
      (const __attribute__((address_space(1))) void*)g,
      (__attribute__((address_space(3))) void*)l, 16, 0, 0);
}

// ---------------------------------------------------------------------------
// Transpose (KDIM x DMODEL fp32 row-major) -> (DMODEL x KDIM fp16 hi/lo)
// grid (KDIM/64, DMODEL/64), block 256
// ---------------------------------------------------------------------------
__global__ __launch_bounds__(256) void transpose_split(const float* __restrict__ W,
                                                       _Float16* __restrict__ Th,
                                                       _Float16* __restrict__ Tl) {
  __shared__ float tbuf[64][65];
  const int tid = threadIdx.x;
  const int k0 = blockIdx.x * 64, n0 = blockIdx.y * 64;
#pragma unroll
  for (int j = 0; j < 4; ++j) {
    int ci = tid + 256 * j;
    int r = ci >> 4, c4 = (ci & 15) * 4;
    float4 v = *(const float4*)&W[(size_t)(k0 + r) * DMODEL + n0 + c4];
    tbuf[r][c4 + 0] = v.x; tbuf[r][c4 + 1] = v.y;
    tbuf[r][c4 + 2] = v.z; tbuf[r][c4 + 3] = v.w;
  }
  __syncthreads();
#pragma unroll
  for (int j = 0; j < 2; ++j) {
    int ci = tid + 256 * j;
    int nl = ci >> 3, k8 = (ci & 7) * 8;
    f16x8 hv, lv;
#pragma unroll
    for (int e = 0; e < 8; ++e) {
      float v = tbuf[k8 + e][nl];
      _Float16 hh = (_Float16)v;
      hv[e] = hh;
      lv[e] = (_Float16)(v - (float)hh);
    }
    size_t off = (size_t)(n0 + nl) * KDIM + k0 + k8;
    *(f16x8*)&Th[off] = hv;
    *(f16x8*)&Tl[off] = lv;
  }
}

// ---------------------------------------------------------------------------
// Router: 48 logits per token (fp64 accum -> stable top-k), softmaxes, top-3.
// grid TOK, block 256.
// ---------------------------------------------------------------------------
__global__ __launch_bounds__(256) void router_kernel(const float* __restrict__ X,
                                                     const float* __restrict__ Wi,
                                                     const float* __restrict__ Wp,
                                                     const float* __restrict__ Wo,
                                                     float* __restrict__ in_w,
                                                     float* __restrict__ out_w,
                                                     int* __restrict__ pidx) {
  __shared__ float xs[1024];
  __shared__ double lg[48];
  const int t = blockIdx.x, tid = threadIdx.x;
  const int wid = tid >> 6, lane = tid & 63;
#pragma unroll
  for (int j = 0; j < 4; ++j) {
    int d = tid + 256 * j;
    xs[d] = X[(size_t)t * DMODEL + d];
  }
  __syncthreads();
  for (int i = wid; i < 48; i += 4) {
    const float* wrow = (i < 8)  ? Wi + (size_t)i * DMODEL
                      : (i < 40) ? Wp + (size_t)(i - 8) * DMODEL
                                 : Wo + (size_t)(i - 40) * DMODEL;
    double s = 0.0;
#pragma unroll
    for (int j = 0; j < 16; ++j) { int d = lane + 64 * j; s += (double)xs[d] * (double)wrow[d]; }
#pragma unroll
    for (int mm = 32; mm >= 1; mm >>= 1) s += __shfl_xor(s, mm);
    if (lane == 0) lg[i] = s;
  }
  __syncthreads();
  if (tid == 0) {
    float l[8], m = (float)lg[0];
    for (int i = 0; i < 8; ++i) { l[i] = (float)lg[i]; }
    for (int i = 1; i < 8; ++i) m = fmaxf(m, l[i]);
    float e[8], su = 0.f;
    for (int i = 0; i < 8; ++i) { e[i] = expf(l[i] - m); su += e[i]; }
    for (int i = 0; i < 8; ++i) in_w[t * 8 + i] = e[i] / su;
  } else if (tid == 64) {
    float l[8], m;
    for (int i = 0; i < 8; ++i) l[i] = (float)lg[40 + i];
    m = l[0];
    for (int i = 1; i < 8; ++i) m = fmaxf(m, l[i]);
    float e[8], su = 0.f;
    for (int i = 0; i < 8; ++i) { e[i] = expf(l[i] - m); su += e[i]; }
    for (int i = 0; i < 8; ++i) out_w[t * 8 + i] = e[i] / su;
  } else if (tid == 128) {
    unsigned used = 0;
    for (int j = 0; j < 3; ++j) {
      double best = -1e300; int bi = 0;
      for (int i = 0; i < 32; ++i)
        if (!((used >> i) & 1u) && lg[8 + i] > best) { best = lg[8 + i]; bi = i; }
      used |= 1u << bi;
      pidx[t * 3 + j] = bi;
    }
  }
}

// ---------------------------------------------------------------------------
// 3 sequential Householder reflections, in place on H. grid TOK, block 256.
// h -= 2*v*(h.v)/(v.v + 1e-8)   (matches reference's renormalization)
// ---------------------------------------------------------------------------
__global__ __launch_bounds__(256) void reflect_kernel(float* __restrict__ H,
                                                      const int* __restrict__ pidx,
                                                      const float* __restrict__ vtab) {
  __shared__ float red[8];
  const int t = blockIdx.x, tid = threadIdx.x;
  const int wid = tid >> 6, lane = tid & 63;
  float4 h = *(const float4*)&H[(size_t)t * DMODEL + tid * 4];
  for (int i = 0; i < 3; ++i) {
    int idx = pidx[t * 3 + i];
    float4 vi = *(const float4*)&vtab[(size_t)idx * DMODEL + tid * 4];
    float hv = h.x * vi.x + h.y * vi.y + h.z * vi.z + h.w * vi.w;
    float vv = vi.x * vi.x + vi.y * vi.y + vi.z * vi.z + vi.w * vi.w;
#pragma unroll
    for (int mm = 32; mm >= 1; mm >>= 1) { hv += __shfl_xor(hv, mm); vv += __shfl_xor(vv, mm); }
    if (lane == 0) { red[wid] = hv; red[4 + wid] = vv; }
    __syncthreads();
    float dot = red[0] + red[1] + red[2] + red[3];
    float vn  = red[4] + red[5] + red[6] + red[7];
    __syncthreads();
    float c = 2.f * dot / (vn + 1e-8f);
    h.x -= c * vi.x; h.y -= c * vi.y; h.z -= c * vi.z; h.w -= c * vi.w;
  }
  *(float4*)&H[(size_t)t * DMODEL + tid * 4] = h;
}

// ---------------------------------------------------------------------------
// Fused GEMM: C[4096x1024] = A @ B^T, A[t,k] = wmix[t, k>>10] * src[t, k&1023]
// built on the fly (fp16 hi/lo split in registers -> LDS); B = pre-split
// planes (N x K). BM=BN=128, BK=32, 4 waves (2x2), wave = 64x64 via 4x4
// 16x16x32 frags, 3 MFMA per frag pair (hh, hl, lh).
// grid (32, 8), block 256.
// ---------------------------------------------------------------------------
__global__ __launch_bounds__(256) void gemm_fused(const float* __restrict__ src,
                                                  const float* __restrict__ wmix,
                                                  const _Float16* __restrict__ Bh,
                                                  const _Float16* __restrict__ Bl,
                                                  float* __restrict__ C) {
  __shared__ _Float16 sAh[128 * 32], sAl[128 * 32];
  __shared__ _Float16 sBh[128 * 32], sBl[128 * 32];
  __shared__ float sW[128 * 8];
  const int tid = threadIdx.x;
  const int wid = tid >> 6, lane = tid & 63;
  const int l16 = lane & 15, lhi = lane >> 4;
  const int wr = wid >> 1, wc = wid & 1;
  const int bm = blockIdx.x * 128, bn = blockIdx.y * 128;

  *(float4*)&sW[tid * 4] = *(const float4*)&wmix[(size_t)bm * 8 + tid * 4];

  f32x4 acc[4][4];
#pragma unroll
  for (int i = 0; i < 4; ++i)
#pragma unroll
    for (int j = 0; j < 4; ++j) { f32x4 z = {0.f, 0.f, 0.f, 0.f}; acc[i][j] = z; }
  __syncthreads();   // sW ready

  for (int kt = 0; kt < KDIM; kt += 32) {
    const int n = kt >> 10, d0 = kt & 1023;
    // ---- B staging: global_load_lds, 512 x 16B per plane-pair ----
#pragma unroll
    for (int j = 0; j < 2; ++j) {
      int ci = tid + 256 * j;
      int row = ci >> 2, jc = ci & 3;
      size_t gb = (size_t)(bn + row) * KDIM + kt + jc * 8;
      async16(&Bh[gb], &sBh[ci * 8]);
      async16(&Bl[gb], &sBl[ci * 8]);
    }
    // ---- A staging: load fp32, scale by mixture weight, split hi/lo ----
#pragma unroll
    for (int j = 0; j < 4; ++j) {
      int ci = tid + 256 * j;
      int row = ci >> 3, c4 = (ci & 7) * 4;
      float4 v = *(const float4*)&src[(size_t)(bm + row) * DMODEL + d0 + c4];
      float wv = sW[row * 8 + n];
      f16x4 hvv, lvv;
      float vals[4] = { v.x * wv, v.y * wv, v.z * wv, v.w * wv };
#pragma unroll
      for (int e = 0; e < 4; ++e) {
        _Float16 hh = (_Float16)vals[e];
        hvv[e] = hh;
        lvv[e] = (_Float16)(vals[e] - (float)hh);
      }
      *(f16x4*)&sAh[row * 32 + c4] = hvv;
      *(f16x4*)&sAl[row * 32 + c4] = lvv;
    }
    __syncthreads();
    f16x8 fah[4], fal[4], fbh[4], fbl[4];
#pragma unroll
    for (int mi = 0; mi < 4; ++mi) {
      int row = wr * 64 + mi * 16 + l16;
      fah[mi] = *(const f16x8*)&sAh[row * 32 + lhi * 8];
      fal[mi] = *(const f16x8*)&sAl[row * 32 + lhi * 8];
    }
#pragma unroll
    for (int ni = 0; ni < 4; ++ni) {
      int row = wc * 64 + ni * 16 + l16;
      fbh[ni] = *(const f16x8*)&sBh[row * 32 + lhi * 8];
      fbl[ni] = *(const f16x8*)&sBl[row * 32 + lhi * 8];
    }
#pragma unroll
    for (int mi = 0; mi < 4; ++mi)
#pragma unroll
      for (int ni = 0; ni < 4; ++ni) {
        f32x4 a = acc[mi][ni];
        a = __builtin_amdgcn_mfma_f32_16x16x32_f16(fah[mi], fbh[ni], a, 0, 0, 0);
        a = __builtin_amdgcn_mfma_f32_16x16x32_f16(fah[mi], fbl[ni], a, 0, 0, 0);
        a = __builtin_amdgcn_mfma_f32_16x16x32_f16(fal[mi], fbh[ni], a, 0, 0, 0);
        acc[mi][ni] = a;
      }
    __syncthreads();
  }
#pragma unroll
  for (int mi = 0; mi < 4; ++mi)
#pragma unroll
    for (int ni = 0; ni < 4; ++ni)
#pragma unroll
      for (int r = 0; r < 4; ++r) {
        int row = bm + wr * 64 + mi * 16 + lhi * 4 + r;
        int col = bn + wc * 64 + ni * 16 + l16;
        C[(size_t)row * DMODEL + col] = acc[mi][ni][r];
      }
}

// ---------------------------------------------------------------------------
// Causal flash attention, fp32 VALU. Q/K/V/O are (TOK x 1024), head h in
// cols [h*128,(h+1)*128). 64 q-rows/block, 4 threads/row. grid (S/64, B*H).
// ---------------------------------------------------------------------------
__global__ __launch_bounds__(256) void attn_kernel(const float* __restrict__ Q,
                                                   const float* __restrict__ K,
                                                   const float* __restrict__ V,
                                                   float* __restrict__ O) {
  __shared__ float Ks[32 * 128];
  __shared__ float Vs[32 * 128];
  const int tid = threadIdx.x;
  const int qt = blockIdx.x, bh = blockIdx.y;
  const int b = bh >> 3, h = bh & 7;
  const int qrow = qt * 64 + (tid >> 2);
  const int part = tid & 3;
  const size_t base = (size_t)b * S_LEN * DMODEL + h * 128;
  const float scale = 0.08838834764831845f;  // 1/sqrt(128)
  float4 q[8];
#pragma unroll
  for (int e = 0; e < 8; ++e)
    q[e] = *(const float4*)&Q[base + (size_t)qrow * DMODEL + e * 16 + part * 4];
  float4 o[8];
#pragma unroll
  for (int e = 0; e < 8; ++e) { o[e].x = 0.f; o[e].y = 0.f; o[e].z = 0.f; o[e].w = 0.f; }
  float mrun = -1e30f, lsum = 0.f;
  const int nkt = qt * 2 + 2;
  for (int kt = 0; kt < nkt; ++kt) {
    __syncthreads();
#pragma unroll
    for (int j = 0; j < 4; ++j) {
      int ci = tid + 256 * j;
      int key = ci >> 5, d4 = (ci & 31) * 4;
      size_t g = base + (size_t)(kt * 32 + key) * DMODEL + d4;
      *(float4*)&Ks[key * 128 + d4] = *(const float4*)&K[g];
      *(float4*)&Vs[key * 128 + d4] = *(const float4*)&V[g];
    }
    __syncthreads();
    float sc[32];
#pragma unroll
    for (int j = 0; j < 32; ++j) {
      float s = 0.f;
#pragma unroll
      for (int e = 0; e < 8; ++e) {
        const float4 kv = *(const float4*)&Ks[j * 128 + e * 16 + part * 4];
        s += q[e].x * kv.x + q[e].y * kv.y + q[e].z * kv.z + q[e].w * kv.w;
      }
      s += __shfl_xor(s, 1);
      s += __shfl_xor(s, 2);
      int keyg = kt * 32 + j;
      sc[j] = (keyg <= qrow) ? s * scale : -1e30f;
    }
    float tmax = sc[0];
#pragma unroll
    for (int j = 1; j < 32; ++j) tmax = fmaxf(tmax, sc[j]);
    float mn = fmaxf(mrun, tmax);
    float f = __expf(mrun - mn);
    mrun = mn;
    float rs = 0.f;
#pragma unroll
    for (int j = 0; j < 32; ++j) { sc[j] = __expf(sc[j] - mn); rs += sc[j]; }
    lsum = lsum * f + rs;
#pragma unroll
    for (int e = 0; e < 8; ++e) { o[e].x *= f; o[e].y *= f; o[e].z *= f; o[e].w *= f; }
#pragma unroll
    for (int j = 0; j < 32; ++j) {
      float p = sc[j];
#pragma unroll
      for (int e = 0; e < 8; ++e) {
        const float4 vv = *(const float4*)&Vs[j * 128 + e * 16 + part * 4];
        o[e].x += p * vv.x; o[e].y += p * vv.y; o[e].z += p * vv.z; o[e].w += p * vv.w;
      }
    }
  }
  const float inv = 1.f / lsum;
#pragma unroll
  for (int e = 0; e < 8; ++e) {
    float4 r;
    r.x = o[e].x * inv; r.y = o[e].y * inv; r.z = o[e].z * inv; r.w = o[e].w * inv;
    *(float4*)&O[base + (size_t)qrow * DMODEL + e * 16 + part * 4] = r;
  }
}

// ---------------------------------------------------------------------------
extern "C" void kernel_launch(void* const* d_in, const int* in_sizes, int n_in,
                              void* d_out, int out_size, void* d_ws, size_t ws_size,
                              hipStream_t stream) {
  (void)in_sizes; (void)n_in; (void)out_size;
  const float* x        = (const float*)d_in[0];
  // d_in[1] = mask (causal tril, implemented analytically)
  const float* Wr_in    = (const float*)d_in[2];
  const float* Wr_proc  = (const float*)d_in[3];
  const float* Wr_out   = (const float*)d_in[4];
  const float* WrO_in   = (const float*)d_in[5];
  const float* WrO_proc = (const float*)d_in[6];
  const float* WrO_out  = (const float*)d_in[7];
  const float* Wq_in    = (const float*)d_in[8];
  const float* vq       = (const float*)d_in[9];
  const float* Wq_out   = (const float*)d_in[10];
  const float* Wk_in    = (const float*)d_in[11];
  const float* vk       = (const float*)d_in[12];
  const float* Wk_out   = (const float*)d_in[13];
  const float* Wv_in    = (const float*)d_in[14];
  const float* vv       = (const float*)d_in[15];
  const float* Wv_out   = (const float*)d_in[16];
  const float* Wo_in    = (const float*)d_in[17];
  const float* vo       = (const float*)d_in[18];
  const float* Wo_out   = (const float*)d_in[19];

  // --- workspace carve (~101.4 MB total) ---
  char* wsbase = (char*)d_ws;
  size_t off = 0;
  auto carve = [&](size_t bytes) -> void* {
    void* r = wsbase + off;
    off = (off + bytes + 255) & ~(size_t)255;
    return r;
  };
  const size_t WBYTES = (size_t)KDIM * DMODEL * 2;   // 16.78 MB fp16 plane
  const size_t HBYTES = (size_t)TOK * DMODEL * 4;    // 16.78 MB fp32
  _Float16* WTh = (_Float16*)carve(WBYTES);
  _Float16* WTl = (_Float16*)carve(WBYTES);
  float* b1 = (float*)carve(HBYTES);
  float* b2 = (float*)carve(HBYTES);
  float* b3 = (float*)carve(HBYTES);
  float* b4 = (float*)carve(HBYTES);
  float* iw1 = (float*)carve((size_t)TOK * 8 * 4);
  float* ow1 = (float*)carve((size_t)TOK * 8 * 4);
  float* iw2 = (float*)carve((size_t)TOK * 8 * 4);
  float* ow2 = (float*)carve((size_t)TOK * 8 * 4);
  int* pi1 = (int*)carve((size_t)TOK * 3 * 4);
  int* pi2 = (int*)carve((size_t)TOK * 3 * 4);

  if (off > ws_size) {  // diagnosable failure instead of OOB abort
    hipMemsetAsync(d_out, 0, (size_t)out_size * 4, stream);
    return;
  }

  const dim3 blk(256);
  const dim3 tgrid(KDIM / 64, DMODEL / 64);   // (128, 16)
  const dim3 ggrid(TOK / 128, DMODEL / 128);  // (32, 8)
  const dim3 agrid(S_LEN / 64, 16);           // (32, B*H)

  // router 1 on x
  router_kernel<<<TOK, blk, 0, stream>>>(x, Wr_in, Wr_proc, Wr_out, iw1, ow1, pi1);

  // in-projections
  transpose_split<<<tgrid, blk, 0, stream>>>(Wq_in, WTh, WTl);
  gemm_fused<<<ggrid, blk, 0, stream>>>(x, iw1, WTh, WTl, b1);      // hq
  transpose_split<<<tgrid, blk, 0, stream>>>(Wk_in, WTh, WTl);
  gemm_fused<<<ggrid, blk, 0, stream>>>(x, iw1, WTh, WTl, b2);      // hk
  transpose_split<<<tgrid, blk, 0, stream>>>(Wv_in, WTh, WTl);
  gemm_fused<<<ggrid, blk, 0, stream>>>(x, iw1, WTh, WTl, b3);      // hv

  // reflections + out-projections
  reflect_kernel<<<TOK, blk, 0, stream>>>(b1, pi1, vq);
  transpose_split<<<tgrid, blk, 0, stream>>>(Wq_out, WTh, WTl);
  gemm_fused<<<ggrid, blk, 0, stream>>>(b1, ow1, WTh, WTl, b4);     // Q -> b4
  reflect_kernel<<<TOK, blk, 0, stream>>>(b2, pi1, vk);
  transpose_split<<<tgrid, blk, 0, stream>>>(Wk_out, WTh, WTl);
  gemm_fused<<<ggrid, blk, 0, stream>>>(b2, ow1, WTh, WTl, b1);     // K -> b1
  reflect_kernel<<<TOK, blk, 0, stream>>>(b3, pi1, vv);
  transpose_split<<<tgrid, blk, 0, stream>>>(Wv_out, WTh, WTl);
  gemm_fused<<<ggrid, blk, 0, stream>>>(b3, ow1, WTh, WTl, b2);     // V -> b2

  // attention: Q=b4 K=b1 V=b2 -> O=b3
  attn_kernel<<<agrid, blk, 0, stream>>>(b4, b1, b2, b3);

  // router 2 on O, final circuit
  router_kernel<<<TOK, blk, 0, stream>>>(b3, WrO_in, WrO_proc, WrO_out, iw2, ow2, pi2);
  transpose_split<<<tgrid, blk, 0, stream>>>(Wo_in, WTh, WTl);
  gemm_fused<<<ggrid, blk, 0, stream>>>(b3, iw2, WTh, WTl, b4);     // h_o -> b4
  reflect_kernel<<<TOK, blk, 0, stream>>>(b4, pi2, vo);
  transpose_split<<<tgrid, blk, 0, stream>>>(Wo_out, WTh, WTl);
  gemm_fused<<<ggrid, blk, 0, stream>>>(b4, ow2, WTh, WTl, (float*)d_out);
}

// Round 3
// 3055.157 us; speedup vs baseline: 1.3081x; 1.3081x over previous
//
#include <hip/hip_runtime.h>

// ---------------------------------------------------------------------------
// NeuronCircuitQKV round 3: MFMA flash attention + GEMM LDS swizzles.
// B=2 S=2048 D=R=1024 H=8 DH=128 NI=8 NP=32 NO=8 K=3
// Precision: all GEMM-shaped math in 2xfp16-split MFMA (rel err ~2^-22,
// fp32-faithful for the top-k routers); routers fp64-accum; reflections fp32.
// ---------------------------------------------------------------------------

typedef __attribute__((ext_vector_type(4))) float f32x4;
typedef _Float16 f16x8 __attribute__((ext_vector_type(8)));
typedef _Float16 f16x4 __attribute__((ext_vector_type(4)));

static constexpr int S_LEN  = 2048;
static constexpr int TOK    = 4096;   // B*S
static constexpr int DMODEL = 1024;
static constexpr int KDIM   = 8192;   // 8 experts * 1024

__device__ __forceinline__ void async16(const void* g, void* l) {
  __builtin_amdgcn_global_load_lds(
      (const __attribute__((address_space(1))) void*)g,
      (__attribute__((address_space(3))) void*)l, 16, 0, 0);
}

// ---------------------------------------------------------------------------
// Transpose (KDIM x DMODEL fp32) -> (DMODEL x KDIM fp16 hi/lo planes)
// ---------------------------------------------------------------------------
__global__ __launch_bounds__(256) void transpose_split(const float* __restrict__ W,
                                                       _Float16* __restrict__ Th,
                                                       _Float16* __restrict__ Tl) {
  __shared__ float tbuf[64][65];
  const int tid = threadIdx.x;
  const int k0 = blockIdx.x * 64, n0 = blockIdx.y * 64;
#pragma unroll
  for (int j = 0; j < 4; ++j) {
    int ci = tid + 256 * j;
    int r = ci >> 4, c4 = (ci & 15) * 4;
    float4 v = *(const float4*)&W[(size_t)(k0 + r) * DMODEL + n0 + c4];
    tbuf[r][c4 + 0] = v.x; tbuf[r][c4 + 1] = v.y;
    tbuf[r][c4 + 2] = v.z; tbuf[r][c4 + 3] = v.w;
  }
  __syncthreads();
#pragma unroll
  for (int j = 0; j < 2; ++j) {
    int ci = tid + 256 * j;
    int nl = ci >> 3, k8 = (ci & 7) * 8;
    f16x8 hv, lv;
#pragma unroll
    for (int e = 0; e < 8; ++e) {
      float v = tbuf[k8 + e][nl];
      _Float16 hh = (_Float16)v;
      hv[e] = hh;
      lv[e] = (_Float16)(v - (float)hh);
    }
    size_t off = (size_t)(n0 + nl) * KDIM + k0 + k8;
    *(f16x8*)&Th[off] = hv;
    *(f16x8*)&Tl[off] = lv;
  }
}

// ---------------------------------------------------------------------------
// Router: 48 logits (fp64 accum -> stable top-k), softmaxes, top-3.
// ---------------------------------------------------------------------------
__global__ __launch_bounds__(256) void router_kernel(const float* __restrict__ X,
                                                     const float* __restrict__ Wi,
                                                     const float* __restrict__ Wp,
                                                     const float* __restrict__ Wo,
                                                     float* __restrict__ in_w,
                                                     float* __restrict__ out_w,
                                                     int* __restrict__ pidx) {
  __shared__ float xs[1024];
  __shared__ double lg[48];
  const int t = blockIdx.x, tid = threadIdx.x;
  const int wid = tid >> 6, lane = tid & 63;
#pragma unroll
  for (int j = 0; j < 4; ++j) {
    int d = tid + 256 * j;
    xs[d] = X[(size_t)t * DMODEL + d];
  }
  __syncthreads();
  for (int i = wid; i < 48; i += 4) {
    const float* wrow = (i < 8)  ? Wi + (size_t)i * DMODEL
                      : (i < 40) ? Wp + (size_t)(i - 8) * DMODEL
                                 : Wo + (size_t)(i - 40) * DMODEL;
    double s = 0.0;
#pragma unroll
    for (int j = 0; j < 16; ++j) { int d = lane + 64 * j; s += (double)xs[d] * (double)wrow[d]; }
#pragma unroll
    for (int mm = 32; mm >= 1; mm >>= 1) s += __shfl_xor(s, mm);
    if (lane == 0) lg[i] = s;
  }
  __syncthreads();
  if (tid == 0) {
    float l[8], m;
    for (int i = 0; i < 8; ++i) l[i] = (float)lg[i];
    m = l[0];
    for (int i = 1; i < 8; ++i) m = fmaxf(m, l[i]);
    float e[8], su = 0.f;
    for (int i = 0; i < 8; ++i) { e[i] = expf(l[i] - m); su += e[i]; }
    for (int i = 0; i < 8; ++i) in_w[t * 8 + i] = e[i] / su;
  } else if (tid == 64) {
    float l[8], m;
    for (int i = 0; i < 8; ++i) l[i] = (float)lg[40 + i];
    m = l[0];
    for (int i = 1; i < 8; ++i) m = fmaxf(m, l[i]);
    float e[8], su = 0.f;
    for (int i = 0; i < 8; ++i) { e[i] = expf(l[i] - m); su += e[i]; }
    for (int i = 0; i < 8; ++i) out_w[t * 8 + i] = e[i] / su;
  } else if (tid == 128) {
    unsigned used = 0;
    for (int j = 0; j < 3; ++j) {
      double best = -1e300; int bi = 0;
      for (int i = 0; i < 32; ++i)
        if (!((used >> i) & 1u) && lg[8 + i] > best) { best = lg[8 + i]; bi = i; }
      used |= 1u << bi;
      pidx[t * 3 + j] = bi;
    }
  }
}

// ---------------------------------------------------------------------------
// 3 sequential Householder reflections, in place.
// ---------------------------------------------------------------------------
__global__ __launch_bounds__(256) void reflect_kernel(float* __restrict__ H,
                                                      const int* __restrict__ pidx,
                                                      const float* __restrict__ vtab) {
  __shared__ float red[8];
  const int t = blockIdx.x, tid = threadIdx.x;
  const int wid = tid >> 6, lane = tid & 63;
  float4 h = *(const float4*)&H[(size_t)t * DMODEL + tid * 4];
  for (int i = 0; i < 3; ++i) {
    int idx = pidx[t * 3 + i];
    float4 vi = *(const float4*)&vtab[(size_t)idx * DMODEL + tid * 4];
    float hv = h.x * vi.x + h.y * vi.y + h.z * vi.z + h.w * vi.w;
    float vv = vi.x * vi.x + vi.y * vi.y + vi.z * vi.z + vi.w * vi.w;
#pragma unroll
    for (int mm = 32; mm >= 1; mm >>= 1) { hv += __shfl_xor(hv, mm); vv += __shfl_xor(vv, mm); }
    if (lane == 0) { red[wid] = hv; red[4 + wid] = vv; }
    __syncthreads();
    float dot = red[0] + red[1] + red[2] + red[3];
    float vn  = red[4] + red[5] + red[6] + red[7];
    __syncthreads();
    float c = 2.f * dot / (vn + 1e-8f);
    h.x -= c * vi.x; h.y -= c * vi.y; h.z -= c * vi.z; h.w -= c * vi.w;
  }
  *(float4*)&H[(size_t)t * DMODEL + tid * 4] = h;
}

// ---------------------------------------------------------------------------
// Fused GEMM with LDS XOR swizzle (A: write+read; B: pre-swizzled global src).
// C = A @ B^T, A[t,k] = wmix[t,k>>10]*src[t,k&1023], split on the fly.
// ---------------------------------------------------------------------------
__global__ __launch_bounds__(256) void gemm_fused(const float* __restrict__ src,
                                                  const float* __restrict__ wmix,
                                                  const _Float16* __restrict__ Bh,
                                                  const _Float16* __restrict__ Bl,
                                                  float* __restrict__ C) {
  __shared__ _Float16 sAh[128 * 32], sAl[128 * 32];
  __shared__ _Float16 sBh[128 * 32], sBl[128 * 32];
  __shared__ float sW[128 * 8];
  const int tid = threadIdx.x;
  const int wid = tid >> 6, lane = tid & 63;
  const int l16 = lane & 15, lhi = lane >> 4;
  const int wr = wid >> 1, wc = wid & 1;
  const int bm = blockIdx.x * 128, bn = blockIdx.y * 128;

  *(float4*)&sW[tid * 4] = *(const float4*)&wmix[(size_t)bm * 8 + tid * 4];

  f32x4 acc[4][4];
#pragma unroll
  for (int i = 0; i < 4; ++i)
#pragma unroll
    for (int j = 0; j < 4; ++j) { f32x4 z = {0.f, 0.f, 0.f, 0.f}; acc[i][j] = z; }
  __syncthreads();

  for (int kt = 0; kt < KDIM; kt += 32) {
    const int n = kt >> 10, d0 = kt & 1023;
    // B staging: pre-swizzle the 16B-chunk index in the GLOBAL address so the
    // linear global_load_lds dest yields the swizzled LDS layout (rule #21).
#pragma unroll
    for (int j = 0; j < 2; ++j) {
      int ci = tid + 256 * j;
      int row = ci >> 2, jc = ci & 3;
      int jcs = jc ^ (row & 3);
      size_t gb = (size_t)(bn + row) * KDIM + kt + jcs * 8;
      async16(&Bh[gb], &sBh[ci * 8]);
      async16(&Bl[gb], &sBl[ci * 8]);
    }
    // A staging: load fp32, scale, split, swizzled ds_write (8B chunks).
#pragma unroll
    for (int j = 0; j < 4; ++j) {
      int ci = tid + 256 * j;
      int row = ci >> 3, c4 = (ci & 7) * 4;
      float4 v = *(const float4*)&src[(size_t)(bm + row) * DMODEL + d0 + c4];
      float wv = sW[row * 8 + n];
      f16x4 hvv, lvv;
      float vals[4] = { v.x * wv, v.y * wv, v.z * wv, v.w * wv };
#pragma unroll
      for (int e = 0; e < 4; ++e) {
        _Float16 hh = (_Float16)vals[e];
        hvv[e] = hh;
        lvv[e] = (_Float16)(vals[e] - (float)hh);
      }
      int sidx = row * 32 + (c4 ^ ((row & 3) * 8));
      *(f16x4*)&sAh[sidx] = hvv;
      *(f16x4*)&sAl[sidx] = lvv;
    }
    __syncthreads();
    f16x8 fah[4], fal[4], fbh[4], fbl[4];
#pragma unroll
    for (int mi = 0; mi < 4; ++mi) {
      int row = wr * 64 + mi * 16 + l16;
      int idx = row * 32 + ((lhi * 8) ^ ((row & 3) * 8));
      fah[mi] = *(const f16x8*)&sAh[idx];
      fal[mi] = *(const f16x8*)&sAl[idx];
    }
#pragma unroll
    for (int ni = 0; ni < 4; ++ni) {
      int row = wc * 64 + ni * 16 + l16;
      int idx = row * 32 + ((lhi * 8) ^ ((row & 3) * 8));
      fbh[ni] = *(const f16x8*)&sBh[idx];
      fbl[ni] = *(const f16x8*)&sBl[idx];
    }
#pragma unroll
    for (int mi = 0; mi < 4; ++mi)
#pragma unroll
      for (int ni = 0; ni < 4; ++ni) {
        f32x4 a = acc[mi][ni];
        a = __builtin_amdgcn_mfma_f32_16x16x32_f16(fah[mi], fbh[ni], a, 0, 0, 0);
        a = __builtin_amdgcn_mfma_f32_16x16x32_f16(fah[mi], fbl[ni], a, 0, 0, 0);
        a = __builtin_amdgcn_mfma_f32_16x16x32_f16(fal[mi], fbh[ni], a, 0, 0, 0);
        acc[mi][ni] = a;
      }
    __syncthreads();
  }
#pragma unroll
  for (int mi = 0; mi < 4; ++mi)
#pragma unroll
    for (int ni = 0; ni < 4; ++ni)
#pragma unroll
      for (int r = 0; r < 4; ++r) {
        int row = bm + wr * 64 + mi * 16 + lhi * 4 + r;
        int col = bn + wc * 64 + ni * 16 + l16;
        C[(size_t)row * DMODEL + col] = acc[mi][ni][r];
      }
}

// ---------------------------------------------------------------------------
// V transpose: V (TOK x 1024, [b][t][h][dh]) -> Vt [b][h][dh][t] fp32.
// grid (S/64, DH/64=2, B*H), block 256.
// ---------------------------------------------------------------------------
__global__ __launch_bounds__(256) void vtrans_kernel(const float* __restrict__ V,
                                                     float* __restrict__ Vt) {
  __shared__ float tbuf[64][65];
  const int tid = threadIdx.x;
  const int t0 = blockIdx.x * 64, d0 = blockIdx.y * 64, bh = blockIdx.z;
  const int b = bh >> 3, h = bh & 7;
#pragma unroll
  for (int j = 0; j < 4; ++j) {
    int ci = tid + 256 * j;
    int r = ci >> 4, c4 = (ci & 15) * 4;
    float4 v = *(const float4*)&V[(size_t)(b * S_LEN + t0 + r) * DMODEL + h * 128 + d0 + c4];
    tbuf[r][c4 + 0] = v.x; tbuf[r][c4 + 1] = v.y;
    tbuf[r][c4 + 2] = v.z; tbuf[r][c4 + 3] = v.w;
  }
  __syncthreads();
#pragma unroll
  for (int j = 0; j < 4; ++j) {
    int ci = tid + 256 * j;
    int r = ci >> 4, c4 = (ci & 15) * 4;   // r: d-local, c4: t-local
    float4 o;
    o.x = tbuf[c4 + 0][r]; o.y = tbuf[c4 + 1][r];
    o.z = tbuf[c4 + 2][r]; o.w = tbuf[c4 + 3][r];
    *(float4*)&Vt[((size_t)bh * 128 + d0 + r) * S_LEN + t0 + c4] = o;
  }
}

// ---------------------------------------------------------------------------
// MFMA flash attention, split-fp16 (fp32-faithful). QBLK=64 (4 waves x 16 q),
// KBLK=32. K tile + V^T tile in LDS (split planes, XOR-swizzled); P bounced
// via per-wave LDS. Causal per-wave tile bounds; LPT (long q-tiles first).
// grid (S/64, B*H), block 256.
// ---------------------------------------------------------------------------
__global__ __launch_bounds__(256) void attn_kernel(const float* __restrict__ Q,
                                                   const float* __restrict__ Kg,
                                                   const float* __restrict__ Vt,
                                                   float* __restrict__ O) {
  __shared__ _Float16 sKh[32 * 128], sKl[32 * 128];   // [k][d] rows 256B
  __shared__ _Float16 sVh[128 * 32], sVl[128 * 32];   // [d][t] rows 64B
  __shared__ _Float16 sPh[4 * 16 * 32], sPl[4 * 16 * 32];  // per-wave [q][k]
  const int tid = threadIdx.x;
  const int wid = tid >> 6, lane = tid & 63;
  const int l16 = lane & 15, lhi = lane >> 4;
  const int qt = (gridDim.x - 1) - blockIdx.x;        // LPT: longest first
  const int bh = blockIdx.y;
  const int b = bh >> 3, h = bh & 7;
  const size_t qkbase = (size_t)b * S_LEN * DMODEL + h * 128;
  const float scale = 0.08838834764831845f;           // 1/sqrt(128)

  // ---- Q fragments (held in registers, hi/lo split) ----
  const int qrow = qt * 64 + wid * 16 + l16;
  f16x8 qh[4], ql[4];
#pragma unroll
  for (int kk = 0; kk < 4; ++kk) {
    const float* qp = &Q[qkbase + (size_t)qrow * DMODEL + kk * 32 + lhi * 8];
    float4 a = *(const float4*)qp;
    float4 c = *(const float4*)(qp + 4);
    float v[8] = {a.x, a.y, a.z, a.w, c.x, c.y, c.z, c.w};
#pragma unroll
    for (int e = 0; e < 8; ++e) {
      _Float16 hh = (_Float16)v[e];
      qh[kk][e] = hh;
      ql[kk][e] = (_Float16)(v[e] - (float)hh);
    }
  }

  f32x4 of[8];
#pragma unroll
  for (int i = 0; i < 8; ++i) { f32x4 z = {0.f, 0.f, 0.f, 0.f}; of[i] = z; }
  float m_[4], l_[4];
#pragma unroll
  for (int r = 0; r < 4; ++r) { m_[r] = -1e30f; l_[r] = 0.f; }

  const int ntw = qt * 2 + 1 + (wid >> 1);            // this wave's tile count
  const int NT  = qt * 2 + 2;                         // block tile count

  for (int kt = 0; kt < NT; ++kt) {
    __syncthreads();
    // ---- stage K tile (32 k x 128 d), swizzle: f16idx = k*128 + (d ^ (k&7)*8)
#pragma unroll
    for (int j = 0; j < 4; ++j) {
      int ci = tid + 256 * j;
      int k = ci >> 5, d4 = (ci & 31) * 4;
      float4 v = *(const float4*)&Kg[qkbase + (size_t)(kt * 32 + k) * DMODEL + d4];
      f16x4 hv, lv;
      float vals[4] = {v.x, v.y, v.z, v.w};
#pragma unroll
      for (int e = 0; e < 4; ++e) {
        _Float16 hh = (_Float16)vals[e];
        hv[e] = hh;
        lv[e] = (_Float16)(vals[e] - (float)hh);
      }
      int idx = k * 128 + (d4 ^ ((k & 7) * 8));
      *(f16x4*)&sKh[idx] = hv;
      *(f16x4*)&sKl[idx] = lv;
    }
    // ---- stage V^T tile (128 d x 32 t), swizzle: f16idx = d*32 + (t ^ ((d>>1)&3)*8)
#pragma unroll
    for (int j = 0; j < 4; ++j) {
      int ci = tid + 256 * j;
      int d = ci >> 3, t4 = (ci & 7) * 4;
      float4 v = *(const float4*)&Vt[((size_t)bh * 128 + d) * S_LEN + kt * 32 + t4];
      f16x4 hv, lv;
      float vals[4] = {v.x, v.y, v.z, v.w};
#pragma unroll
      for (int e = 0; e < 4; ++e) {
        _Float16 hh = (_Float16)vals[e];
        hv[e] = hh;
        lv[e] = (_Float16)(vals[e] - (float)hh);
      }
      int idx = d * 32 + (t4 ^ (((d >> 1) & 3) * 8));
      *(f16x4*)&sVh[idx] = hv;
      *(f16x4*)&sVl[idx] = lv;
    }
    __syncthreads();

    if (kt < ntw) {
      // ---- QK^T: S[16q x 32k] as two 16x16 frags ----
      f32x4 s0 = {0.f, 0.f, 0.f, 0.f}, s1 = {0.f, 0.f, 0.f, 0.f};
#pragma unroll
      for (int kk = 0; kk < 4; ++kk) {
        int col = (kk * 32 + lhi * 8);
        int i0 = l16 * 128 + (col ^ ((l16 & 7) * 8));
        int i1 = (16 + l16) * 128 + (col ^ (((16 + l16) & 7) * 8));
        f16x8 kb0h = *(const f16x8*)&sKh[i0];
        f16x8 kb0l = *(const f16x8*)&sKl[i0];
        f16x8 kb1h = *(const f16x8*)&sKh[i1];
        f16x8 kb1l = *(const f16x8*)&sKl[i1];
        s0 = __builtin_amdgcn_mfma_f32_16x16x32_f16(qh[kk], kb0h, s0, 0, 0, 0);
        s0 = __builtin_amdgcn_mfma_f32_16x16x32_f16(qh[kk], kb0l, s0, 0, 0, 0);
        s0 = __builtin_amdgcn_mfma_f32_16x16x32_f16(ql[kk], kb0h, s0, 0, 0, 0);
        s1 = __builtin_amdgcn_mfma_f32_16x16x32_f16(qh[kk], kb1h, s1, 0, 0, 0);
        s1 = __builtin_amdgcn_mfma_f32_16x16x32_f16(qh[kk], kb1l, s1, 0, 0, 0);
        s1 = __builtin_amdgcn_mfma_f32_16x16x32_f16(ql[kk], kb1h, s1, 0, 0, 0);
      }
      // ---- scale + causal mask (only the wave's last tile is partial) ----
      const int qg = qt * 64 + wid * 16 + (lane >> 4) * 4;   // +r
      if (kt == ntw - 1) {
#pragma unroll
        for (int r = 0; r < 4; ++r) {
          int q = qg + r;
          int k0 = kt * 32 + l16, k1 = k0 + 16;
          s0[r] = (k0 <= q) ? s0[r] * scale : -1e30f;
          s1[r] = (k1 <= q) ? s1[r] * scale : -1e30f;
        }
      } else {
#pragma unroll
        for (int r = 0; r < 4; ++r) { s0[r] *= scale; s1[r] *= scale; }
      }
      // ---- online softmax (row spans 16 lanes of this group) ----
      float p0[4], p1[4], fr[4];
#pragma unroll
      for (int r = 0; r < 4; ++r) {
        float rm = fmaxf(s0[r], s1[r]);
        rm = fmaxf(rm, __shfl_xor(rm, 1));
        rm = fmaxf(rm, __shfl_xor(rm, 2));
        rm = fmaxf(rm, __shfl_xor(rm, 4));
        rm = fmaxf(rm, __shfl_xor(rm, 8));
        float mn = fmaxf(m_[r], rm);
        fr[r] = __expf(m_[r] - mn);
        m_[r] = mn;
        p0[r] = __expf(s0[r] - mn);
        p1[r] = __expf(s1[r] - mn);
        float rs = p0[r] + p1[r];
        rs += __shfl_xor(rs, 1);
        rs += __shfl_xor(rs, 2);
        rs += __shfl_xor(rs, 4);
        rs += __shfl_xor(rs, 8);
        l_[r] = l_[r] * fr[r] + rs;
      }
#pragma unroll
      for (int i = 0; i < 8; ++i)
#pragma unroll
        for (int r = 0; r < 4; ++r) of[i][r] *= fr[r];
      // ---- split P, bounce via per-wave LDS (C-layout -> A-layout) ----
#pragma unroll
      for (int r = 0; r < 4; ++r) {
        int q = (lane >> 4) * 4 + r;
        int swz = ((q >> 1) & 3) * 8;
        int c0 = l16, c1 = 16 + l16;
        _Float16 h0 = (_Float16)p0[r];
        _Float16 h1 = (_Float16)p1[r];
        sPh[wid * 512 + q * 32 + (c0 ^ swz)] = h0;
        sPl[wid * 512 + q * 32 + (c0 ^ swz)] = (_Float16)(p0[r] - (float)h0);
        sPh[wid * 512 + q * 32 + (c1 ^ swz)] = h1;
        sPl[wid * 512 + q * 32 + (c1 ^ swz)] = (_Float16)(p1[r] - (float)h1);
      }
      int pidxr = wid * 512 + l16 * 32 + ((lhi * 8) ^ (((l16 >> 1) & 3) * 8));
      f16x8 pah = *(const f16x8*)&sPh[pidxr];
      f16x8 pal = *(const f16x8*)&sPl[pidxr];
      // ---- PV: O[16q x 128d] += P @ V ----
#pragma unroll
      for (int d16 = 0; d16 < 8; ++d16) {
        int d = d16 * 16 + l16;
        int vidx = d * 32 + ((lhi * 8) ^ (((d >> 1) & 3) * 8));
        f16x8 vbh = *(const f16x8*)&sVh[vidx];
        f16x8 vbl = *(const f16x8*)&sVl[vidx];
        f32x4 a = of[d16];
        a = __builtin_amdgcn_mfma_f32_16x16x32_f16(pah, vbh, a, 0, 0, 0);
        a = __builtin_amdgcn_mfma_f32_16x16x32_f16(pah, vbl, a, 0, 0, 0);
        a = __builtin_amdgcn_mfma_f32_16x16x32_f16(pal, vbh, a, 0, 0, 0);
        of[d16] = a;
      }
    }
  }
  // ---- normalize + write ----
  float inv[4];
#pragma unroll
  for (int r = 0; r < 4; ++r) inv[r] = 1.f / l_[r];
  const int qg = qt * 64 + wid * 16 + (lane >> 4) * 4;
#pragma unroll
  for (int d16 = 0; d16 < 8; ++d16)
#pragma unroll
    for (int r = 0; r < 4; ++r)
      O[qkbase + (size_t)(qg + r) * DMODEL + d16 * 16 + l16] = of[d16][r] * inv[r];
}

// ---------------------------------------------------------------------------
extern "C" void kernel_launch(void* const* d_in, const int* in_sizes, int n_in,
                              void* d_out, int out_size, void* d_ws, size_t ws_size,
                              hipStream_t stream) {
  (void)in_sizes; (void)n_in; (void)out_size;
  const float* x        = (const float*)d_in[0];
  const float* Wr_in    = (const float*)d_in[2];
  const float* Wr_proc  = (const float*)d_in[3];
  const float* Wr_out   = (const float*)d_in[4];
  const float* WrO_in   = (const float*)d_in[5];
  const float* WrO_proc = (const float*)d_in[6];
  const float* WrO_out  = (const float*)d_in[7];
  const float* Wq_in    = (const float*)d_in[8];
  const float* vq       = (const float*)d_in[9];
  const float* Wq_out   = (const float*)d_in[10];
  const float* Wk_in    = (const float*)d_in[11];
  const float* vk       = (const float*)d_in[12];
  const float* Wk_out   = (const float*)d_in[13];
  const float* Wv_in    = (const float*)d_in[14];
  const float* vv       = (const float*)d_in[15];
  const float* Wv_out   = (const float*)d_in[16];
  const float* Wo_in    = (const float*)d_in[17];
  const float* vo       = (const float*)d_in[18];
  const float* Wo_out   = (const float*)d_in[19];

  char* wsbase = (char*)d_ws;
  size_t off = 0;
  auto carve = [&](size_t bytes) -> void* {
    void* r = wsbase + off;
    off = (off + bytes + 255) & ~(size_t)255;
    return r;
  };
  const size_t WBYTES = (size_t)KDIM * DMODEL * 2;
  const size_t HBYTES = (size_t)TOK * DMODEL * 4;
  _Float16* WTh = (_Float16*)carve(WBYTES);
  _Float16* WTl = (_Float16*)carve(WBYTES);
  float* b1 = (float*)carve(HBYTES);
  float* b2 = (float*)carve(HBYTES);
  float* b3 = (float*)carve(HBYTES);
  float* b4 = (float*)carve(HBYTES);
  float* iw1 = (float*)carve((size_t)TOK * 8 * 4);
  float* ow1 = (float*)carve((size_t)TOK * 8 * 4);
  float* iw2 = (float*)carve((size_t)TOK * 8 * 4);
  float* ow2 = (float*)carve((size_t)TOK * 8 * 4);
  int* pi1 = (int*)carve((size_t)TOK * 3 * 4);
  int* pi2 = (int*)carve((size_t)TOK * 3 * 4);

  if (off > ws_size) {
    hipMemsetAsync(d_out, 0, (size_t)out_size * 4, stream);
    return;
  }

  const dim3 blk(256);
  const dim3 tgrid(KDIM / 64, DMODEL / 64);
  const dim3 ggrid(TOK / 128, DMODEL / 128);
  const dim3 vgrid(S_LEN / 64, 2, 16);
  const dim3 agrid(S_LEN / 64, 16);

  router_kernel<<<TOK, blk, 0, stream>>>(x, Wr_in, Wr_proc, Wr_out, iw1, ow1, pi1);

  transpose_split<<<tgrid, blk, 0, stream>>>(Wq_in, WTh, WTl);
  gemm_fused<<<ggrid, blk, 0, stream>>>(x, iw1, WTh, WTl, b1);      // hq
  transpose_split<<<tgrid, blk, 0, stream>>>(Wk_in, WTh, WTl);
  gemm_fused<<<ggrid, blk, 0, stream>>>(x, iw1, WTh, WTl, b2);      // hk
  transpose_split<<<tgrid, blk, 0, stream>>>(Wv_in, WTh, WTl);
  gemm_fused<<<ggrid, blk, 0, stream>>>(x, iw1, WTh, WTl, b3);      // hv

  reflect_kernel<<<TOK, blk, 0, stream>>>(b1, pi1, vq);
  transpose_split<<<tgrid, blk, 0, stream>>>(Wq_out, WTh, WTl);
  gemm_fused<<<ggrid, blk, 0, stream>>>(b1, ow1, WTh, WTl, b4);     // Q -> b4
  reflect_kernel<<<TOK, blk, 0, stream>>>(b2, pi1, vk);
  transpose_split<<<tgrid, blk, 0, stream>>>(Wk_out, WTh, WTl);
  gemm_fused<<<ggrid, blk, 0, stream>>>(b2, ow1, WTh, WTl, b1);     // K -> b1
  reflect_kernel<<<TOK, blk, 0, stream>>>(b3, pi1, vv);
  transpose_split<<<tgrid, blk, 0, stream>>>(Wv_out, WTh, WTl);
  gemm_fused<<<ggrid, blk, 0, stream>>>(b3, ow1, WTh, WTl, b2);     // V -> b2

  vtrans_kernel<<<vgrid, blk, 0, stream>>>(b2, b3);                 // Vt -> b3
  attn_kernel<<<agrid, blk, 0, stream>>>(b4, b1, b3, b2);           // O -> b2

  router_kernel<<<TOK, blk, 0, stream>>>(b2, WrO_in, WrO_proc, WrO_out, iw2, ow2, pi2);
  transpose_split<<<tgrid, blk, 0, stream>>>(Wo_in, WTh, WTl);
  gemm_fused<<<ggrid, blk, 0, stream>>>(b2, iw2, WTh, WTl, b4);     // h_o
  reflect_kernel<<<TOK, blk, 0, stream>>>(b4, pi2, vo);
  transpose_split<<<tgrid, blk, 0, stream>>>(Wo_out, WTh, WTl);
  gemm_fused<<<ggrid, blk, 0, stream>>>(b4, ow2, WTh, WTl, (float*)d_out);
}

// Round 4
// 2077.102 us; speedup vs baseline: 1.9240x; 1.4709x over previous
//
#include <hip/hip_runtime.h>

// ---------------------------------------------------------------------------
// NeuronCircuitQKV round 4: split-K=2 GEMM (2 blocks/CU), padded A-LDS,
// 2-way B swizzle, XCD-pane-local block remap.
// B=2 S=2048 D=R=1024 H=8 DH=128 NI=8 NP=32 NO=8 K=3
// Precision: 2xfp16-split MFMA everywhere GEMM-shaped (rel err ~2^-22);
// routers fp64-accum; reflections fp32. Split-K partial sum of exactly two
// fp32 values is order-exact -> deterministic.
// ---------------------------------------------------------------------------

typedef __attribute__((ext_vector_type(4))) float f32x4;
typedef _Float16 f16x8 __attribute__((ext_vector_type(8)));
typedef _Float16 f16x4 __attribute__((ext_vector_type(4)));

static constexpr int S_LEN  = 2048;
static constexpr int TOK    = 4096;   // B*S
static constexpr int DMODEL = 1024;
static constexpr int KDIM   = 8192;   // 8 experts * 1024

__device__ __forceinline__ void async16(const void* g, void* l) {
  __builtin_amdgcn_global_load_lds(
      (const __attribute__((address_space(1))) void*)g,
      (__attribute__((address_space(3))) void*)l, 16, 0, 0);
}

// ---------------------------------------------------------------------------
// Transpose (KDIM x DMODEL fp32) -> (DMODEL x KDIM fp16 hi/lo planes)
// ---------------------------------------------------------------------------
__global__ __launch_bounds__(256) void transpose_split(const float* __restrict__ W,
                                                       _Float16* __restrict__ Th,
                                                       _Float16* __restrict__ Tl) {
  __shared__ float tbuf[64][65];
  const int tid = threadIdx.x;
  const int k0 = blockIdx.x * 64, n0 = blockIdx.y * 64;
#pragma unroll
  for (int j = 0; j < 4; ++j) {
    int ci = tid + 256 * j;
    int r = ci >> 4, c4 = (ci & 15) * 4;
    float4 v = *(const float4*)&W[(size_t)(k0 + r) * DMODEL + n0 + c4];
    tbuf[r][c4 + 0] = v.x; tbuf[r][c4 + 1] = v.y;
    tbuf[r][c4 + 2] = v.z; tbuf[r][c4 + 3] = v.w;
  }
  __syncthreads();
#pragma unroll
  for (int j = 0; j < 2; ++j) {
    int ci = tid + 256 * j;
    int nl = ci >> 3, k8 = (ci & 7) * 8;
    f16x8 hv, lv;
#pragma unroll
    for (int e = 0; e < 8; ++e) {
      float v = tbuf[k8 + e][nl];
      _Float16 hh = (_Float16)v;
      hv[e] = hh;
      lv[e] = (_Float16)(v - (float)hh);
    }
    size_t off = (size_t)(n0 + nl) * KDIM + k0 + k8;
    *(f16x8*)&Th[off] = hv;
    *(f16x8*)&Tl[off] = lv;
  }
}

// ---------------------------------------------------------------------------
// Router: 48 logits (fp64 accum -> stable top-k), softmaxes, top-3.
// ---------------------------------------------------------------------------
__global__ __launch_bounds__(256) void router_kernel(const float* __restrict__ X,
                                                     const float* __restrict__ Wi,
                                                     const float* __restrict__ Wp,
                                                     const float* __restrict__ Wo,
                                                     float* __restrict__ in_w,
                                                     float* __restrict__ out_w,
                                                     int* __restrict__ pidx) {
  __shared__ float xs[1024];
  __shared__ double lg[48];
  const int t = blockIdx.x, tid = threadIdx.x;
  const int wid = tid >> 6, lane = tid & 63;
#pragma unroll
  for (int j = 0; j < 4; ++j) {
    int d = tid + 256 * j;
    xs[d] = X[(size_t)t * DMODEL + d];
  }
  __syncthreads();
  for (int i = wid; i < 48; i += 4) {
    const float* wrow = (i < 8)  ? Wi + (size_t)i * DMODEL
                      : (i < 40) ? Wp + (size_t)(i - 8) * DMODEL
                                 : Wo + (size_t)(i - 40) * DMODEL;
    double s = 0.0;
#pragma unroll
    for (int j = 0; j < 16; ++j) { int d = lane + 64 * j; s += (double)xs[d] * (double)wrow[d]; }
#pragma unroll
    for (int mm = 32; mm >= 1; mm >>= 1) s += __shfl_xor(s, mm);
    if (lane == 0) lg[i] = s;
  }
  __syncthreads();
  if (tid == 0) {
    float l[8], m;
    for (int i = 0; i < 8; ++i) l[i] = (float)lg[i];
    m = l[0];
    for (int i = 1; i < 8; ++i) m = fmaxf(m, l[i]);
    float e[8], su = 0.f;
    for (int i = 0; i < 8; ++i) { e[i] = expf(l[i] - m); su += e[i]; }
    for (int i = 0; i < 8; ++i) in_w[t * 8 + i] = e[i] / su;
  } else if (tid == 64) {
    float l[8], m;
    for (int i = 0; i < 8; ++i) l[i] = (float)lg[40 + i];
    m = l[0];
    for (int i = 1; i < 8; ++i) m = fmaxf(m, l[i]);
    float e[8], su = 0.f;
    for (int i = 0; i < 8; ++i) { e[i] = expf(l[i] - m); su += e[i]; }
    for (int i = 0; i < 8; ++i) out_w[t * 8 + i] = e[i] / su;
  } else if (tid == 128) {
    unsigned used = 0;
    for (int j = 0; j < 3; ++j) {
      double best = -1e300; int bi = 0;
      for (int i = 0; i < 32; ++i)
        if (!((used >> i) & 1u) && lg[8 + i] > best) { best = lg[8 + i]; bi = i; }
      used |= 1u << bi;
      pidx[t * 3 + j] = bi;
    }
  }
}

// ---------------------------------------------------------------------------
// Fused: h = Pa + Pb (split-K reduce), then 3 Householder reflections -> dst.
// ---------------------------------------------------------------------------
__global__ __launch_bounds__(256) void reflect_kernel(const float* __restrict__ Pa,
                                                      const float* __restrict__ Pb,
                                                      const int* __restrict__ pidx,
                                                      const float* __restrict__ vtab,
                                                      float* __restrict__ dst) {
  __shared__ float red[8];
  const int t = blockIdx.x, tid = threadIdx.x;
  const int wid = tid >> 6, lane = tid & 63;
  float4 ha = *(const float4*)&Pa[(size_t)t * DMODEL + tid * 4];
  float4 hb = *(const float4*)&Pb[(size_t)t * DMODEL + tid * 4];
  float4 h = {ha.x + hb.x, ha.y + hb.y, ha.z + hb.z, ha.w + hb.w};
  for (int i = 0; i < 3; ++i) {
    int idx = pidx[t * 3 + i];
    float4 vi = *(const float4*)&vtab[(size_t)idx * DMODEL + tid * 4];
    float hv = h.x * vi.x + h.y * vi.y + h.z * vi.z + h.w * vi.w;
    float vv = vi.x * vi.x + vi.y * vi.y + vi.z * vi.z + vi.w * vi.w;
#pragma unroll
    for (int mm = 32; mm >= 1; mm >>= 1) { hv += __shfl_xor(hv, mm); vv += __shfl_xor(vv, mm); }
    if (lane == 0) { red[wid] = hv; red[4 + wid] = vv; }
    __syncthreads();
    float dot = red[0] + red[1] + red[2] + red[3];
    float vn  = red[4] + red[5] + red[6] + red[7];
    __syncthreads();
    float c = 2.f * dot / (vn + 1e-8f);
    h.x -= c * vi.x; h.y -= c * vi.y; h.z -= c * vi.z; h.w -= c * vi.w;
  }
  *(float4*)&dst[(size_t)t * DMODEL + tid * 4] = h;
}

// ---------------------------------------------------------------------------
// Split-K reduce: c = a + b (order-exact, deterministic). grid 4096, blk 256.
// ---------------------------------------------------------------------------
__global__ __launch_bounds__(256) void reduce_add(const float* __restrict__ a,
                                                  const float* __restrict__ b,
                                                  float* __restrict__ c) {
  size_t i = ((size_t)blockIdx.x * 256 + threadIdx.x) * 4;
  float4 va = *(const float4*)&a[i];
  float4 vb = *(const float4*)&b[i];
  float4 vc = {va.x + vb.x, va.y + vb.y, va.z + vb.z, va.w + vb.w};
  *(float4*)&c[i] = vc;
}

// ---------------------------------------------------------------------------
// Split-fp16 GEMM, split-K=2: Cp[bz][4096x1024] = A @ B(half)^T.
// A[t,k] = wmix[t,k>>10]*src[t,k&1023] built on the fly.
// BM=BN=128, BK=32, 4 waves. A-LDS padded to stride 40 f16 (2-way banks);
// B staged via global_load_lds with (row>>1)&3 chunk pre-swizzle (2-way).
// Grid (32,8,2) remapped so each XCD owns 2 complete B panes.
// ---------------------------------------------------------------------------
__global__ __launch_bounds__(256) void gemm_fused(const float* __restrict__ src,
                                                  const float* __restrict__ wmix,
                                                  const _Float16* __restrict__ Bh,
                                                  const _Float16* __restrict__ Bl,
                                                  float* __restrict__ Cp0,
                                                  float* __restrict__ Cp1) {
  __shared__ _Float16 sAh[128 * 40], sAl[128 * 40];
  __shared__ _Float16 sBh[128 * 32], sBl[128 * 32];
  __shared__ float sW[128 * 8];
  const int tid = threadIdx.x;
  const int wid = tid >> 6, lane = tid & 63;
  const int l16 = lane & 15, lhi = lane >> 4;
  const int wr = wid >> 1, wc = wid & 1;
  // Bijective XCD remap: 512 wgs, 64/XCD; XCD k -> bz=k>>2, by in {2k,2k+1}&7.
  const int fid = blockIdx.x + (blockIdx.y << 5) + (blockIdx.z << 8);
  const int wg  = ((fid & 7) << 6) + (fid >> 3);
  const int bm = (wg & 31) * 128;
  const int bn = ((wg >> 5) & 7) * 128;
  const int kbase = (wg >> 8) * 4096;
  float* __restrict__ Cp = (wg >> 8) ? Cp1 : Cp0;

  *(float4*)&sW[tid * 4] = *(const float4*)&wmix[(size_t)bm * 8 + tid * 4];

  f32x4 acc[4][4];
#pragma unroll
  for (int i = 0; i < 4; ++i)
#pragma unroll
    for (int j = 0; j < 4; ++j) { f32x4 z = {0.f, 0.f, 0.f, 0.f}; acc[i][j] = z; }
  __syncthreads();

  for (int kt = 0; kt < 4096; kt += 32) {
    const int kg = kbase + kt;
    const int n = kg >> 10, d0 = kg & 1023;
    // B staging: pre-swizzled global chunk so linear LDS dest = swizzled layout
#pragma unroll
    for (int j = 0; j < 2; ++j) {
      int ci = tid + 256 * j;
      int row = ci >> 2, jc = ci & 3;
      int jcs = jc ^ ((row >> 1) & 3);
      size_t gb = (size_t)(bn + row) * KDIM + kg + jcs * 8;
      async16(&Bh[gb], &sBh[ci * 8]);
      async16(&Bl[gb], &sBl[ci * 8]);
    }
    // A staging: fp32 load, mixture-scale, hi/lo split, padded ds_write
#pragma unroll
    for (int j = 0; j < 4; ++j) {
      int ci = tid + 256 * j;
      int row = ci >> 3, c4 = (ci & 7) * 4;
      float4 v = *(const float4*)&src[(size_t)(bm + row) * DMODEL + d0 + c4];
      float wv = sW[row * 8 + n];
      f16x4 hvv, lvv;
      float vals[4] = { v.x * wv, v.y * wv, v.z * wv, v.w * wv };
#pragma unroll
      for (int e = 0; e < 4; ++e) {
        _Float16 hh = (_Float16)vals[e];
        hvv[e] = hh;
        lvv[e] = (_Float16)(vals[e] - (float)hh);
      }
      int sidx = row * 40 + c4;
      *(f16x4*)&sAh[sidx] = hvv;
      *(f16x4*)&sAl[sidx] = lvv;
    }
    __syncthreads();
    f16x8 fah[4], fal[4], fbh[4], fbl[4];
#pragma unroll
    for (int mi = 0; mi < 4; ++mi) {
      int row = wr * 64 + mi * 16 + l16;
      int idx = row * 40 + lhi * 8;
      fah[mi] = *(const f16x8*)&sAh[idx];
      fal[mi] = *(const f16x8*)&sAl[idx];
    }
#pragma unroll
    for (int ni = 0; ni < 4; ++ni) {
      int row = wc * 64 + ni * 16 + l16;
      int idx = row * 32 + ((lhi ^ ((row >> 1) & 3)) * 8);
      fbh[ni] = *(const f16x8*)&sBh[idx];
      fbl[ni] = *(const f16x8*)&sBl[idx];
    }
#pragma unroll
    for (int mi = 0; mi < 4; ++mi)
#pragma unroll
      for (int ni = 0; ni < 4; ++ni) {
        f32x4 a = acc[mi][ni];
        a = __builtin_amdgcn_mfma_f32_16x16x32_f16(fah[mi], fbh[ni], a, 0, 0, 0);
        a = __builtin_amdgcn_mfma_f32_16x16x32_f16(fah[mi], fbl[ni], a, 0, 0, 0);
        a = __builtin_amdgcn_mfma_f32_16x16x32_f16(fal[mi], fbh[ni], a, 0, 0, 0);
        acc[mi][ni] = a;
      }
    __syncthreads();
  }
#pragma unroll
  for (int mi = 0; mi < 4; ++mi)
#pragma unroll
    for (int ni = 0; ni < 4; ++ni)
#pragma unroll
      for (int r = 0; r < 4; ++r) {
        int row = bm + wr * 64 + mi * 16 + lhi * 4 + r;
        int col = bn + wc * 64 + ni * 16 + l16;
        Cp[(size_t)row * DMODEL + col] = acc[mi][ni][r];
      }
}

// ---------------------------------------------------------------------------
// V transpose + split-K reduce: V = Va+Vb (TOK x 1024, [b][t][h][dh]) ->
// Vt [b][h][dh][t] fp32. grid (S/64, DH/64=2, B*H), block 256.
// ---------------------------------------------------------------------------
__global__ __launch_bounds__(256) void vtrans_kernel(const float* __restrict__ Va,
                                                     const float* __restrict__ Vb,
                                                     float* __restrict__ Vt) {
  __shared__ float tbuf[64][65];
  const int tid = threadIdx.x;
  const int t0 = blockIdx.x * 64, d0 = blockIdx.y * 64, bh = blockIdx.z;
  const int b = bh >> 3, h = bh & 7;
#pragma unroll
  for (int j = 0; j < 4; ++j) {
    int ci = tid + 256 * j;
    int r = ci >> 4, c4 = (ci & 15) * 4;
    size_t g = (size_t)(b * S_LEN + t0 + r) * DMODEL + h * 128 + d0 + c4;
    float4 va = *(const float4*)&Va[g];
    float4 vb = *(const float4*)&Vb[g];
    tbuf[r][c4 + 0] = va.x + vb.x; tbuf[r][c4 + 1] = va.y + vb.y;
    tbuf[r][c4 + 2] = va.z + vb.z; tbuf[r][c4 + 3] = va.w + vb.w;
  }
  __syncthreads();
#pragma unroll
  for (int j = 0; j < 4; ++j) {
    int ci = tid + 256 * j;
    int r = ci >> 4, c4 = (ci & 15) * 4;   // r: d-local, c4: t-local
    float4 o;
    o.x = tbuf[c4 + 0][r]; o.y = tbuf[c4 + 1][r];
    o.z = tbuf[c4 + 2][r]; o.w = tbuf[c4 + 3][r];
    *(float4*)&Vt[((size_t)bh * 128 + d0 + r) * S_LEN + t0 + c4] = o;
  }
}

// ---------------------------------------------------------------------------
// MFMA flash attention, split-fp16 (fp32-faithful). QBLK=64 (4 waves x 16 q),
// KBLK=32. K tile + V^T tile in LDS (split planes, XOR-swizzled); P bounced
// via per-wave LDS. Causal per-wave tile bounds; LPT (long q-tiles first).
// grid (S/64, B*H), block 256.
// ---------------------------------------------------------------------------
__global__ __launch_bounds__(256) void attn_kernel(const float* __restrict__ Q,
                                                   const float* __restrict__ Kg,
                                                   const float* __restrict__ Vt,
                                                   float* __restrict__ O) {
  __shared__ _Float16 sKh[32 * 128], sKl[32 * 128];
  __shared__ _Float16 sVh[128 * 32], sVl[128 * 32];
  __shared__ _Float16 sPh[4 * 16 * 32], sPl[4 * 16 * 32];
  const int tid = threadIdx.x;
  const int wid = tid >> 6, lane = tid & 63;
  const int l16 = lane & 15, lhi = lane >> 4;
  const int qt = (gridDim.x - 1) - blockIdx.x;
  const int bh = blockIdx.y;
  const int b = bh >> 3, h = bh & 7;
  const size_t qkbase = (size_t)b * S_LEN * DMODEL + h * 128;
  const float scale = 0.08838834764831845f;  // 1/sqrt(128)

  const int qrow = qt * 64 + wid * 16 + l16;
  f16x8 qh[4], ql[4];
#pragma unroll
  for (int kk = 0; kk < 4; ++kk) {
    const float* qp = &Q[qkbase + (size_t)qrow * DMODEL + kk * 32 + lhi * 8];
    float4 a = *(const float4*)qp;
    float4 c = *(const float4*)(qp + 4);
    float v[8] = {a.x, a.y, a.z, a.w, c.x, c.y, c.z, c.w};
#pragma unroll
    for (int e = 0; e < 8; ++e) {
      _Float16 hh = (_Float16)v[e];
      qh[kk][e] = hh;
      ql[kk][e] = (_Float16)(v[e] - (float)hh);
    }
  }

  f32x4 of[8];
#pragma unroll
  for (int i = 0; i < 8; ++i) { f32x4 z = {0.f, 0.f, 0.f, 0.f}; of[i] = z; }
  float m_[4], l_[4];
#pragma unroll
  for (int r = 0; r < 4; ++r) { m_[r] = -1e30f; l_[r] = 0.f; }

  const int ntw = qt * 2 + 1 + (wid >> 1);
  const int NT  = qt * 2 + 2;

  for (int kt = 0; kt < NT; ++kt) {
    __syncthreads();
#pragma unroll
    for (int j = 0; j < 4; ++j) {
      int ci = tid + 256 * j;
      int k = ci >> 5, d4 = (ci & 31) * 4;
      float4 v = *(const float4*)&Kg[qkbase + (size_t)(kt * 32 + k) * DMODEL + d4];
      f16x4 hv, lv;
      float vals[4] = {v.x, v.y, v.z, v.w};
#pragma unroll
      for (int e = 0; e < 4; ++e) {
        _Float16 hh = (_Float16)vals[e];
        hv[e] = hh;
        lv[e] = (_Float16)(vals[e] - (float)hh);
      }
      int idx = k * 128 + (d4 ^ ((k & 7) * 8));
      *(f16x4*)&sKh[idx] = hv;
      *(f16x4*)&sKl[idx] = lv;
    }
#pragma unroll
    for (int j = 0; j < 4; ++j) {
      int ci = tid + 256 * j;
      int d = ci >> 3, t4 = (ci & 7) * 4;
      float4 v = *(const float4*)&Vt[((size_t)bh * 128 + d) * S_LEN + kt * 32 + t4];
      f16x4 hv, lv;
      float vals[4] = {v.x, v.y, v.z, v.w};
#pragma unroll
      for (int e = 0; e < 4; ++e) {
        _Float16 hh = (_Float16)vals[e];
        hv[e] = hh;
        lv[e] = (_Float16)(vals[e] - (float)hh);
      }
      int idx = d * 32 + (t4 ^ (((d >> 1) & 3) * 8));
      *(f16x4*)&sVh[idx] = hv;
      *(f16x4*)&sVl[idx] = lv;
    }
    __syncthreads();

    if (kt < ntw) {
      f32x4 s0 = {0.f, 0.f, 0.f, 0.f}, s1 = {0.f, 0.f, 0.f, 0.f};
#pragma unroll
      for (int kk = 0; kk < 4; ++kk) {
        int col = (kk * 32 + lhi * 8);
        int i0 = l16 * 128 + (col ^ ((l16 & 7) * 8));
        int i1 = (16 + l16) * 128 + (col ^ (((16 + l16) & 7) * 8));
        f16x8 kb0h = *(const f16x8*)&sKh[i0];
        f16x8 kb0l = *(const f16x8*)&sKl[i0];
        f16x8 kb1h = *(const f16x8*)&sKh[i1];
        f16x8 kb1l = *(const f16x8*)&sKl[i1];
        s0 = __builtin_amdgcn_mfma_f32_16x16x32_f16(qh[kk], kb0h, s0, 0, 0, 0);
        s0 = __builtin_amdgcn_mfma_f32_16x16x32_f16(qh[kk], kb0l, s0, 0, 0, 0);
        s0 = __builtin_amdgcn_mfma_f32_16x16x32_f16(ql[kk], kb0h, s0, 0, 0, 0);
        s1 = __builtin_amdgcn_mfma_f32_16x16x32_f16(qh[kk], kb1h, s1, 0, 0, 0);
        s1 = __builtin_amdgcn_mfma_f32_16x16x32_f16(qh[kk], kb1l, s1, 0, 0, 0);
        s1 = __builtin_amdgcn_mfma_f32_16x16x32_f16(ql[kk], kb1h, s1, 0, 0, 0);
      }
      const int qg = qt * 64 + wid * 16 + (lane >> 4) * 4;
      if (kt == ntw - 1) {
#pragma unroll
        for (int r = 0; r < 4; ++r) {
          int q = qg + r;
          int k0 = kt * 32 + l16, k1 = k0 + 16;
          s0[r] = (k0 <= q) ? s0[r] * scale : -1e30f;
          s1[r] = (k1 <= q) ? s1[r] * scale : -1e30f;
        }
      } else {
#pragma unroll
        for (int r = 0; r < 4; ++r) { s0[r] *= scale; s1[r] *= scale; }
      }
      float p0[4], p1[4], fr[4];
#pragma unroll
      for (int r = 0; r < 4; ++r) {
        float rm = fmaxf(s0[r], s1[r]);
        rm = fmaxf(rm, __shfl_xor(rm, 1));
        rm = fmaxf(rm, __shfl_xor(rm, 2));
        rm = fmaxf(rm, __shfl_xor(rm, 4));
        rm = fmaxf(rm, __shfl_xor(rm, 8));
        float mn = fmaxf(m_[r], rm);
        fr[r] = __expf(m_[r] - mn);
        m_[r] = mn;
        p0[r] = __expf(s0[r] - mn);
        p1[r] = __expf(s1[r] - mn);
        float rs = p0[r] + p1[r];
        rs += __shfl_xor(rs, 1);
        rs += __shfl_xor(rs, 2);
        rs += __shfl_xor(rs, 4);
        rs += __shfl_xor(rs, 8);
        l_[r] = l_[r] * fr[r] + rs;
      }
#pragma unroll
      for (int i = 0; i < 8; ++i)
#pragma unroll
        for (int r = 0; r < 4; ++r) of[i][r] *= fr[r];
#pragma unroll
      for (int r = 0; r < 4; ++r) {
        int q = (lane >> 4) * 4 + r;
        int swz = ((q >> 1) & 3) * 8;
        int c0 = l16, c1 = 16 + l16;
        _Float16 h0 = (_Float16)p0[r];
        _Float16 h1 = (_Float16)p1[r];
        sPh[wid * 512 + q * 32 + (c0 ^ swz)] = h0;
        sPl[wid * 512 + q * 32 + (c0 ^ swz)] = (_Float16)(p0[r] - (float)h0);
        sPh[wid * 512 + q * 32 + (c1 ^ swz)] = h1;
        sPl[wid * 512 + q * 32 + (c1 ^ swz)] = (_Float16)(p1[r] - (float)h1);
      }
      int pidxr = wid * 512 + l16 * 32 + ((lhi * 8) ^ (((l16 >> 1) & 3) * 8));
      f16x8 pah = *(const f16x8*)&sPh[pidxr];
      f16x8 pal = *(const f16x8*)&sPl[pidxr];
#pragma unroll
      for (int d16 = 0; d16 < 8; ++d16) {
        int d = d16 * 16 + l16;
        int vidx = d * 32 + ((lhi * 8) ^ (((d >> 1) & 3) * 8));
        f16x8 vbh = *(const f16x8*)&sVh[vidx];
        f16x8 vbl = *(const f16x8*)&sVl[vidx];
        f32x4 a = of[d16];
        a = __builtin_amdgcn_mfma_f32_16x16x32_f16(pah, vbh, a, 0, 0, 0);
        a = __builtin_amdgcn_mfma_f32_16x16x32_f16(pah, vbl, a, 0, 0, 0);
        a = __builtin_amdgcn_mfma_f32_16x16x32_f16(pal, vbh, a, 0, 0, 0);
        of[d16] = a;
      }
    }
  }
  float inv[4];
#pragma unroll
  for (int r = 0; r < 4; ++r) inv[r] = 1.f / l_[r];
  const int qg = qt * 64 + wid * 16 + (lane >> 4) * 4;
#pragma unroll
  for (int d16 = 0; d16 < 8; ++d16)
#pragma unroll
    for (int r = 0; r < 4; ++r)
      O[qkbase + (size_t)(qg + r) * DMODEL + d16 * 16 + l16] = of[d16][r] * inv[r];
}

// ---------------------------------------------------------------------------
extern "C" void kernel_launch(void* const* d_in, const int* in_sizes, int n_in,
                              void* d_out, int out_size, void* d_ws, size_t ws_size,
                              hipStream_t stream) {
  (void)in_sizes; (void)n_in; (void)out_size;
  const float* x        = (const float*)d_in[0];
  const float* Wr_in    = (const float*)d_in[2];
  const float* Wr_proc  = (const float*)d_in[3];
  const float* Wr_out   = (const float*)d_in[4];
  const float* WrO_in   = (const float*)d_in[5];
  const float* WrO_proc = (const float*)d_in[6];
  const float* WrO_out  = (const float*)d_in[7];
  const float* Wq_in    = (const float*)d_in[8];
  const float* vq       = (const float*)d_in[9];
  const float* Wq_out   = (const float*)d_in[10];
  const float* Wk_in    = (const float*)d_in[11];
  const float* vk       = (const float*)d_in[12];
  const float* Wk_out   = (const float*)d_in[13];
  const float* Wv_in    = (const float*)d_in[14];
  const float* vv       = (const float*)d_in[15];
  const float* Wv_out   = (const float*)d_in[16];
  const float* Wo_in    = (const float*)d_in[17];
  const float* vo       = (const float*)d_in[18];
  const float* Wo_out   = (const float*)d_in[19];

  char* wsbase = (char*)d_ws;
  size_t off = 0;
  auto carve = [&](size_t bytes) -> void* {
    void* r = wsbase + off;
    off = (off + bytes + 255) & ~(size_t)255;
    return r;
  };
  const size_t WBYTES = (size_t)KDIM * DMODEL * 2;   // 16.78 MB fp16 plane
  const size_t HBYTES = (size_t)TOK * DMODEL * 4;    // 16.78 MB fp32
  _Float16* WTh = (_Float16*)carve(WBYTES);
  _Float16* WTl = (_Float16*)carve(WBYTES);
  float* c0 = (float*)carve(HBYTES);
  float* c1 = (float*)carve(HBYTES);
  float* r1 = (float*)carve(HBYTES);
  float* r2 = (float*)carve(HBYTES);
  float* r3 = (float*)carve(HBYTES);
  float* iw1 = (float*)carve((size_t)TOK * 8 * 4);
  float* ow1 = (float*)carve((size_t)TOK * 8 * 4);
  float* iw2 = (float*)carve((size_t)TOK * 8 * 4);
  float* ow2 = (float*)carve((size_t)TOK * 8 * 4);
  int* pi1 = (int*)carve((size_t)TOK * 3 * 4);
  int* pi2 = (int*)carve((size_t)TOK * 3 * 4);

  if (off > ws_size) {   // diagnosable failure instead of OOB abort
    hipMemsetAsync(d_out, 0, (size_t)out_size * 4, stream);
    return;
  }

  const dim3 blk(256);
  const dim3 tgrid(KDIM / 64, DMODEL / 64);        // (128, 16)
  const dim3 ggrid(TOK / 128, DMODEL / 128, 2);    // (32, 8, 2) split-K
  const dim3 rgrid(TOK * DMODEL / (256 * 4));      // 4096
  const dim3 vgrid(S_LEN / 64, 2, 16);
  const dim3 agrid(S_LEN / 64, 16);

  // router 1 on x
  router_kernel<<<TOK, blk, 0, stream>>>(x, Wr_in, Wr_proc, Wr_out, iw1, ow1, pi1);

  // in-projections + reflections (reflect fuses split-K reduce)
  transpose_split<<<tgrid, blk, 0, stream>>>(Wq_in, WTh, WTl);
  gemm_fused<<<ggrid, blk, 0, stream>>>(x, iw1, WTh, WTl, c0, c1);
  reflect_kernel<<<TOK, blk, 0, stream>>>(c0, c1, pi1, vq, r1);
  transpose_split<<<tgrid, blk, 0, stream>>>(Wk_in, WTh, WTl);
  gemm_fused<<<ggrid, blk, 0, stream>>>(x, iw1, WTh, WTl, c0, c1);
  reflect_kernel<<<TOK, blk, 0, stream>>>(c0, c1, pi1, vk, r2);
  transpose_split<<<tgrid, blk, 0, stream>>>(Wv_in, WTh, WTl);
  gemm_fused<<<ggrid, blk, 0, stream>>>(x, iw1, WTh, WTl, c0, c1);
  reflect_kernel<<<TOK, blk, 0, stream>>>(c0, c1, pi1, vv, r3);

  // out-projections
  transpose_split<<<tgrid, blk, 0, stream>>>(Wq_out, WTh, WTl);
  gemm_fused<<<ggrid, blk, 0, stream>>>(r1, ow1, WTh, WTl, c0, c1);
  reduce_add<<<rgrid, blk, 0, stream>>>(c0, c1, r1);               // Q -> r1
  transpose_split<<<tgrid, blk, 0, stream>>>(Wk_out, WTh, WTl);
  gemm_fused<<<ggrid, blk, 0, stream>>>(r2, ow1, WTh, WTl, c0, c1);
  reduce_add<<<rgrid, blk, 0, stream>>>(c0, c1, r2);               // K -> r2
  transpose_split<<<tgrid, blk, 0, stream>>>(Wv_out, WTh, WTl);
  gemm_fused<<<ggrid, blk, 0, stream>>>(r3, ow1, WTh, WTl, c0, c1);
  vtrans_kernel<<<vgrid, blk, 0, stream>>>(c0, c1, r3);            // Vt -> r3

  // attention: Q=r1 K=r2 Vt=r3 -> O=c0
  attn_kernel<<<agrid, blk, 0, stream>>>(r1, r2, r3, c0);

  // router 2 on O, final circuit
  router_kernel<<<TOK, blk, 0, stream>>>(c0, WrO_in, WrO_proc, WrO_out, iw2, ow2, pi2);
  transpose_split<<<tgrid, blk, 0, stream>>>(Wo_in, WTh, WTl);
  gemm_fused<<<ggrid, blk, 0, stream>>>(c0, iw2, WTh, WTl, c1, r2);  // partials c1,r2
  reflect_kernel<<<TOK, blk, 0, stream>>>(c1, r2, pi2, vo, r1);
  transpose_split<<<tgrid, blk, 0, stream>>>(Wo_out, WTh, WTl);
  gemm_fused<<<ggrid, blk, 0, stream>>>(r1, ow2, WTh, WTl, c0, c1);
  reduce_add<<<rgrid, blk, 0, stream>>>(c0, c1, (float*)d_out);
}

// Round 5
// 1934.179 us; speedup vs baseline: 2.0662x; 1.0739x over previous
//
#include <hip/hip_runtime.h>

// ---------------------------------------------------------------------------
// NeuronCircuitQKV round 5: pure-DMA GEMM staging + Horner mixture rescale.
// B=2 S=2048 D=R=1024 H=8 DH=128 NI=8 NP=32 NO=8 K=3
// A operand = pre-split fp16 hi/lo planes of the UNSCALED source; the per-
// expert mixture weight is applied as a per-pane accumulator rescale
// (Horner: acc = acc*(w_n/w_{n+1}) + P_{n+1}, final *w_last). Both A and B
// tiles staged via global_load_lds (pre-swizzled source). 3 MFMA per product
// (hh, hl, lh) keeps rel err ~2^-22 for the top-k routers.
// ---------------------------------------------------------------------------

typedef __attribute__((ext_vector_type(4))) float f32x4;
typedef _Float16 f16x8 __attribute__((ext_vector_type(8)));
typedef _Float16 f16x4 __attribute__((ext_vector_type(4)));

static constexpr int S_LEN  = 2048;
static constexpr int TOK    = 4096;   // B*S
static constexpr int DMODEL = 1024;
static constexpr int KDIM   = 8192;   // 8 experts * 1024

__device__ __forceinline__ void async16(const void* g, void* l) {
  __builtin_amdgcn_global_load_lds(
      (const __attribute__((address_space(1))) void*)g,
      (__attribute__((address_space(3))) void*)l, 16, 0, 0);
}

// ---------------------------------------------------------------------------
// fp32 -> fp16 hi/lo planes (elementwise). grid TOK*DMODEL/1024, block 256.
// ---------------------------------------------------------------------------
__global__ __launch_bounds__(256) void split_kernel(const float* __restrict__ X,
                                                    _Float16* __restrict__ Xh,
                                                    _Float16* __restrict__ Xl) {
  size_t i = ((size_t)blockIdx.x * 256 + threadIdx.x) * 4;
  float4 v = *(const float4*)&X[i];
  float a[4] = {v.x, v.y, v.z, v.w};
  f16x4 hv, lv;
#pragma unroll
  for (int e = 0; e < 4; ++e) {
    _Float16 hh = (_Float16)a[e];
    hv[e] = hh;
    lv[e] = (_Float16)(a[e] - (float)hh);
  }
  *(f16x4*)&Xh[i] = hv;
  *(f16x4*)&Xl[i] = lv;
}

// ---------------------------------------------------------------------------
// Transpose (KDIM x DMODEL fp32) -> (DMODEL x KDIM fp16 hi/lo planes)
// ---------------------------------------------------------------------------
__global__ __launch_bounds__(256) void transpose_split(const float* __restrict__ W,
                                                       _Float16* __restrict__ Th,
                                                       _Float16* __restrict__ Tl) {
  __shared__ float tbuf[64][65];
  const int tid = threadIdx.x;
  const int k0 = blockIdx.x * 64, n0 = blockIdx.y * 64;
#pragma unroll
  for (int j = 0; j < 4; ++j) {
    int ci = tid + 256 * j;
    int r = ci >> 4, c4 = (ci & 15) * 4;
    float4 v = *(const float4*)&W[(size_t)(k0 + r) * DMODEL + n0 + c4];
    tbuf[r][c4 + 0] = v.x; tbuf[r][c4 + 1] = v.y;
    tbuf[r][c4 + 2] = v.z; tbuf[r][c4 + 3] = v.w;
  }
  __syncthreads();
#pragma unroll
  for (int j = 0; j < 2; ++j) {
    int ci = tid + 256 * j;
    int nl = ci >> 3, k8 = (ci & 7) * 8;
    f16x8 hv, lv;
#pragma unroll
    for (int e = 0; e < 8; ++e) {
      float v = tbuf[k8 + e][nl];
      _Float16 hh = (_Float16)v;
      hv[e] = hh;
      lv[e] = (_Float16)(v - (float)hh);
    }
    size_t off = (size_t)(n0 + nl) * KDIM + k0 + k8;
    *(f16x8*)&Th[off] = hv;
    *(f16x8*)&Tl[off] = lv;
  }
}

// ---------------------------------------------------------------------------
// Router: 48 logits (fp64 accum -> stable top-k), softmaxes, top-3.
// ---------------------------------------------------------------------------
__global__ __launch_bounds__(256) void router_kernel(const float* __restrict__ X,
                                                     const float* __restrict__ Wi,
                                                     const float* __restrict__ Wp,
                                                     const float* __restrict__ Wo,
                                                     float* __restrict__ in_w,
                                                     float* __restrict__ out_w,
                                                     int* __restrict__ pidx) {
  __shared__ float xs[1024];
  __shared__ double lg[48];
  const int t = blockIdx.x, tid = threadIdx.x;
  const int wid = tid >> 6, lane = tid & 63;
#pragma unroll
  for (int j = 0; j < 4; ++j) {
    int d = tid + 256 * j;
    xs[d] = X[(size_t)t * DMODEL + d];
  }
  __syncthreads();
  for (int i = wid; i < 48; i += 4) {
    const float* wrow = (i < 8)  ? Wi + (size_t)i * DMODEL
                      : (i < 40) ? Wp + (size_t)(i - 8) * DMODEL
                                 : Wo + (size_t)(i - 40) * DMODEL;
    double s = 0.0;
#pragma unroll
    for (int j = 0; j < 16; ++j) { int d = lane + 64 * j; s += (double)xs[d] * (double)wrow[d]; }
#pragma unroll
    for (int mm = 32; mm >= 1; mm >>= 1) s += __shfl_xor(s, mm);
    if (lane == 0) lg[i] = s;
  }
  __syncthreads();
  if (tid == 0) {
    float l[8], m;
    for (int i = 0; i < 8; ++i) l[i] = (float)lg[i];
    m = l[0];
    for (int i = 1; i < 8; ++i) m = fmaxf(m, l[i]);
    float e[8], su = 0.f;
    for (int i = 0; i < 8; ++i) { e[i] = expf(l[i] - m); su += e[i]; }
    for (int i = 0; i < 8; ++i) in_w[t * 8 + i] = e[i] / su;
  } else if (tid == 64) {
    float l[8], m;
    for (int i = 0; i < 8; ++i) l[i] = (float)lg[40 + i];
    m = l[0];
    for (int i = 1; i < 8; ++i) m = fmaxf(m, l[i]);
    float e[8], su = 0.f;
    for (int i = 0; i < 8; ++i) { e[i] = expf(l[i] - m); su += e[i]; }
    for (int i = 0; i < 8; ++i) out_w[t * 8 + i] = e[i] / su;
  } else if (tid == 128) {
    unsigned used = 0;
    for (int j = 0; j < 3; ++j) {
      double best = -1e300; int bi = 0;
      for (int i = 0; i < 32; ++i)
        if (!((used >> i) & 1u) && lg[8 + i] > best) { best = lg[8 + i]; bi = i; }
      used |= 1u << bi;
      pidx[t * 3 + j] = bi;
    }
  }
}

// ---------------------------------------------------------------------------
// h = Pa + Pb (split-K reduce), 3 Householder reflections, write fp16 hi/lo
// planes of the result (feeds the next GEMM's A operand).
// ---------------------------------------------------------------------------
__global__ __launch_bounds__(256) void reflect_kernel(const float* __restrict__ Pa,
                                                      const float* __restrict__ Pb,
                                                      const int* __restrict__ pidx,
                                                      const float* __restrict__ vtab,
                                                      _Float16* __restrict__ Hh,
                                                      _Float16* __restrict__ Hl) {
  __shared__ float red[8];
  const int t = blockIdx.x, tid = threadIdx.x;
  const int wid = tid >> 6, lane = tid & 63;
  float4 ha = *(const float4*)&Pa[(size_t)t * DMODEL + tid * 4];
  float4 hb = *(const float4*)&Pb[(size_t)t * DMODEL + tid * 4];
  float4 h = {ha.x + hb.x, ha.y + hb.y, ha.z + hb.z, ha.w + hb.w};
  for (int i = 0; i < 3; ++i) {
    int idx = pidx[t * 3 + i];
    float4 vi = *(const float4*)&vtab[(size_t)idx * DMODEL + tid * 4];
    float hv = h.x * vi.x + h.y * vi.y + h.z * vi.z + h.w * vi.w;
    float vv = vi.x * vi.x + vi.y * vi.y + vi.z * vi.z + vi.w * vi.w;
#pragma unroll
    for (int mm = 32; mm >= 1; mm >>= 1) { hv += __shfl_xor(hv, mm); vv += __shfl_xor(vv, mm); }
    if (lane == 0) { red[wid] = hv; red[4 + wid] = vv; }
    __syncthreads();
    float dot = red[0] + red[1] + red[2] + red[3];
    float vn  = red[4] + red[5] + red[6] + red[7];
    __syncthreads();
    float c = 2.f * dot / (vn + 1e-8f);
    h.x -= c * vi.x; h.y -= c * vi.y; h.z -= c * vi.z; h.w -= c * vi.w;
  }
  float a[4] = {h.x, h.y, h.z, h.w};
  f16x4 hv4, lv4;
#pragma unroll
  for (int e = 0; e < 4; ++e) {
    _Float16 hh = (_Float16)a[e];
    hv4[e] = hh;
    lv4[e] = (_Float16)(a[e] - (float)hh);
  }
  *(f16x4*)&Hh[(size_t)t * DMODEL + tid * 4] = hv4;
  *(f16x4*)&Hl[(size_t)t * DMODEL + tid * 4] = lv4;
}

// ---------------------------------------------------------------------------
// Split-K reduce: c = a + b (order-exact). grid 4096, blk 256.
// ---------------------------------------------------------------------------
__global__ __launch_bounds__(256) void reduce_add(const float* __restrict__ a,
                                                  const float* __restrict__ b,
                                                  float* __restrict__ c) {
  size_t i = ((size_t)blockIdx.x * 256 + threadIdx.x) * 4;
  float4 va = *(const float4*)&a[i];
  float4 vb = *(const float4*)&b[i];
  float4 vc = {va.x + vb.x, va.y + vb.y, va.z + vb.z, va.w + vb.w};
  *(float4*)&c[i] = vc;
}

// ---------------------------------------------------------------------------
// Split-fp16 GEMM, split-K=2, pure-DMA staging, Horner mixture rescale.
// Cp[kz] = sum_n w[t,n] * (src @ Bpane_n^T) over this half's 4 panes.
// BM=BN=128, BK=32, 4 waves. A/B tiles both via global_load_lds with
// (row>>1)&3 chunk pre-swizzle (2-way banks). Grid (32,8,2), XCD remap.
// ---------------------------------------------------------------------------
__global__ __launch_bounds__(256, 4) void gemm_planes(const _Float16* __restrict__ Ahp,
                                                      const _Float16* __restrict__ Alp,
                                                      const float* __restrict__ wmix,
                                                      const _Float16* __restrict__ Bh,
                                                      const _Float16* __restrict__ Bl,
                                                      float* __restrict__ Cp0,
                                                      float* __restrict__ Cp1) {
  __shared__ _Float16 sAh[128 * 32], sAl[128 * 32];
  __shared__ _Float16 sBh[128 * 32], sBl[128 * 32];
  __shared__ float sWr[128 * 4];   // [row][p]: p<3 ratio w_p/w_{p+1}, p=3 w_3
  const int tid = threadIdx.x;
  const int wid = tid >> 6, lane = tid & 63;
  const int l16 = lane & 15, lhi = lane >> 4;
  const int wr = wid >> 1, wc = wid & 1;
  // Bijective XCD remap: 512 wgs, 64/XCD, pane-local.
  const int fid = blockIdx.x + (blockIdx.y << 5) + (blockIdx.z << 8);
  const int wg  = ((fid & 7) << 6) + (fid >> 3);
  const int bm = (wg & 31) * 128;
  const int bn = ((wg >> 5) & 7) * 128;
  const int kz = wg >> 8;
  const int kbase = kz * 4096, nb = kz * 4;
  float* __restrict__ Cp = kz ? Cp1 : Cp0;

  for (int i = tid; i < 512; i += 256) {
    int row = i >> 2, p = i & 3;
    const float* w = &wmix[(size_t)(bm + row) * 8 + nb];
    sWr[i] = (p < 3) ? w[p] / w[p + 1] : w[3];
  }

  f32x4 acc[4][4];
#pragma unroll
  for (int i = 0; i < 4; ++i)
#pragma unroll
    for (int j = 0; j < 4; ++j) { f32x4 z = {0.f, 0.f, 0.f, 0.f}; acc[i][j] = z; }

  for (int kt = 0; kt < 4096; kt += 32) {
    const int kg = kbase + kt, d0 = kg & 1023;
#pragma unroll
    for (int j = 0; j < 2; ++j) {
      int ci = tid + 256 * j;
      int row = ci >> 2, jc = ci & 3;
      int jcs = jc ^ ((row >> 1) & 3);
      size_t ga = (size_t)(bm + row) * DMODEL + d0 + jcs * 8;
      size_t gb = (size_t)(bn + row) * KDIM + kg + jcs * 8;
      async16(&Ahp[ga], &sAh[ci * 8]);
      async16(&Alp[ga], &sAl[ci * 8]);
      async16(&Bh[gb], &sBh[ci * 8]);
      async16(&Bl[gb], &sBl[ci * 8]);
    }
    __syncthreads();
    f16x8 fah[4], fal[4], fbh[4], fbl[4];
#pragma unroll
    for (int mi = 0; mi < 4; ++mi) {
      int row = wr * 64 + mi * 16 + l16;
      int idx = row * 32 + ((lhi ^ ((row >> 1) & 3)) * 8);
      fah[mi] = *(const f16x8*)&sAh[idx];
      fal[mi] = *(const f16x8*)&sAl[idx];
    }
#pragma unroll
    for (int ni = 0; ni < 4; ++ni) {
      int row = wc * 64 + ni * 16 + l16;
      int idx = row * 32 + ((lhi ^ ((row >> 1) & 3)) * 8);
      fbh[ni] = *(const f16x8*)&sBh[idx];
      fbl[ni] = *(const f16x8*)&sBl[idx];
    }
#pragma unroll
    for (int mi = 0; mi < 4; ++mi)
#pragma unroll
      for (int ni = 0; ni < 4; ++ni) {
        f32x4 a = acc[mi][ni];
        a = __builtin_amdgcn_mfma_f32_16x16x32_f16(fah[mi], fbh[ni], a, 0, 0, 0);
        a = __builtin_amdgcn_mfma_f32_16x16x32_f16(fah[mi], fbl[ni], a, 0, 0, 0);
        a = __builtin_amdgcn_mfma_f32_16x16x32_f16(fal[mi], fbh[ni], a, 0, 0, 0);
        acc[mi][ni] = a;
      }
    __syncthreads();
    if ((kt & 1023) == 992 && kt != 4064) {   // pane boundary (local p=0,1,2)
      int p = kt >> 10;
#pragma unroll
      for (int mi = 0; mi < 4; ++mi)
#pragma unroll
        for (int r = 0; r < 4; ++r) {
          float s = sWr[(wr * 64 + mi * 16 + lhi * 4 + r) * 4 + p];
#pragma unroll
          for (int ni = 0; ni < 4; ++ni) acc[mi][ni][r] *= s;
        }
    }
  }
#pragma unroll
  for (int mi = 0; mi < 4; ++mi)
#pragma unroll
    for (int r = 0; r < 4; ++r) {
      int rowl = wr * 64 + mi * 16 + lhi * 4 + r;
      float s = sWr[rowl * 4 + 3];   // final scale: w_last of this half
#pragma unroll
      for (int ni = 0; ni < 4; ++ni) {
        int col = bn + wc * 64 + ni * 16 + l16;
        Cp[(size_t)(bm + rowl) * DMODEL + col] = acc[mi][ni][r] * s;
      }
    }
}

// ---------------------------------------------------------------------------
// V transpose + split-K reduce: V = Va+Vb -> Vt [b][h][dh][t] fp32.
// grid (S/64, 2, 16), block 256.
// ---------------------------------------------------------------------------
__global__ __launch_bounds__(256) void vtrans_kernel(const float* __restrict__ Va,
                                                     const float* __restrict__ Vb,
                                                     float* __restrict__ Vt) {
  __shared__ float tbuf[64][65];
  const int tid = threadIdx.x;
  const int t0 = blockIdx.x * 64, d0 = blockIdx.y * 64, bh = blockIdx.z;
  const int b = bh >> 3, h = bh & 7;
#pragma unroll
  for (int j = 0; j < 4; ++j) {
    int ci = tid + 256 * j;
    int r = ci >> 4, c4 = (ci & 15) * 4;
    size_t g = (size_t)(b * S_LEN + t0 + r) * DMODEL + h * 128 + d0 + c4;
    float4 va = *(const float4*)&Va[g];
    float4 vb = *(const float4*)&Vb[g];
    tbuf[r][c4 + 0] = va.x + vb.x; tbuf[r][c4 + 1] = va.y + vb.y;
    tbuf[r][c4 + 2] = va.z + vb.z; tbuf[r][c4 + 3] = va.w + vb.w;
  }
  __syncthreads();
#pragma unroll
  for (int j = 0; j < 4; ++j) {
    int ci = tid + 256 * j;
    int r = ci >> 4, c4 = (ci & 15) * 4;
    float4 o;
    o.x = tbuf[c4 + 0][r]; o.y = tbuf[c4 + 1][r];
    o.z = tbuf[c4 + 2][r]; o.w = tbuf[c4 + 3][r];
    *(float4*)&Vt[((size_t)bh * 128 + d0 + r) * S_LEN + t0 + c4] = o;
  }
}

// ---------------------------------------------------------------------------
// MFMA flash attention, split-fp16. Also emits fp16 hi/lo planes of O for
// the following GEMM. grid (S/64, B*H), block 256.
// ---------------------------------------------------------------------------
__global__ __launch_bounds__(256) void attn_kernel(const float* __restrict__ Q,
                                                   const float* __restrict__ Kg,
                                                   const float* __restrict__ Vt,
                                                   float* __restrict__ O,
                                                   _Float16* __restrict__ Oh,
                                                   _Float16* __restrict__ Ol) {
  __shared__ _Float16 sKh[32 * 128], sKl[32 * 128];
  __shared__ _Float16 sVh[128 * 32], sVl[128 * 32];
  __shared__ _Float16 sPh[4 * 16 * 32], sPl[4 * 16 * 32];
  const int tid = threadIdx.x;
  const int wid = tid >> 6, lane = tid & 63;
  const int l16 = lane & 15, lhi = lane >> 4;
  const int qt = (gridDim.x - 1) - blockIdx.x;
  const int bh = blockIdx.y;
  const int b = bh >> 3, h = bh & 7;
  const size_t qkbase = (size_t)b * S_LEN * DMODEL + h * 128;
  const float scale = 0.08838834764831845f;  // 1/sqrt(128)

  const int qrow = qt * 64 + wid * 16 + l16;
  f16x8 qh[4], ql[4];
#pragma unroll
  for (int kk = 0; kk < 4; ++kk) {
    const float* qp = &Q[qkbase + (size_t)qrow * DMODEL + kk * 32 + lhi * 8];
    float4 a = *(const float4*)qp;
    float4 c = *(const float4*)(qp + 4);
    float v[8] = {a.x, a.y, a.z, a.w, c.x, c.y, c.z, c.w};
#pragma unroll
    for (int e = 0; e < 8; ++e) {
      _Float16 hh = (_Float16)v[e];
      qh[kk][e] = hh;
      ql[kk][e] = (_Float16)(v[e] - (float)hh);
    }
  }

  f32x4 of[8];
#pragma unroll
  for (int i = 0; i < 8; ++i) { f32x4 z = {0.f, 0.f, 0.f, 0.f}; of[i] = z; }
  float m_[4], l_[4];
#pragma unroll
  for (int r = 0; r < 4; ++r) { m_[r] = -1e30f; l_[r] = 0.f; }

  const int ntw = qt * 2 + 1 + (wid >> 1);
  const int NT  = qt * 2 + 2;

  for (int kt = 0; kt < NT; ++kt) {
    __syncthreads();
#pragma unroll
    for (int j = 0; j < 4; ++j) {
      int ci = tid + 256 * j;
      int k = ci >> 5, d4 = (ci & 31) * 4;
      float4 v = *(const float4*)&Kg[qkbase + (size_t)(kt * 32 + k) * DMODEL + d4];
      f16x4 hv, lv;
      float vals[4] = {v.x, v.y, v.z, v.w};
#pragma unroll
      for (int e = 0; e < 4; ++e) {
        _Float16 hh = (_Float16)vals[e];
        hv[e] = hh;
        lv[e] = (_Float16)(vals[e] - (float)hh);
      }
      int idx = k * 128 + (d4 ^ ((k & 7) * 8));
      *(f16x4*)&sKh[idx] = hv;
      *(f16x4*)&sKl[idx] = lv;
    }
#pragma unroll
    for (int j = 0; j < 4; ++j) {
      int ci = tid + 256 * j;
      int d = ci >> 3, t4 = (ci & 7) * 4;
      float4 v = *(const float4*)&Vt[((size_t)bh * 128 + d) * S_LEN + kt * 32 + t4];
      f16x4 hv, lv;
      float vals[4] = {v.x, v.y, v.z, v.w};
#pragma unroll
      for (int e = 0; e < 4; ++e) {
        _Float16 hh = (_Float16)vals[e];
        hv[e] = hh;
        lv[e] = (_Float16)(vals[e] - (float)hh);
      }
      int idx = d * 32 + (t4 ^ (((d >> 1) & 3) * 8));
      *(f16x4*)&sVh[idx] = hv;
      *(f16x4*)&sVl[idx] = lv;
    }
    __syncthreads();

    if (kt < ntw) {
      f32x4 s0 = {0.f, 0.f, 0.f, 0.f}, s1 = {0.f, 0.f, 0.f, 0.f};
#pragma unroll
      for (int kk = 0; kk < 4; ++kk) {
        int col = (kk * 32 + lhi * 8);
        int i0 = l16 * 128 + (col ^ ((l16 & 7) * 8));
        int i1 = (16 + l16) * 128 + (col ^ (((16 + l16) & 7) * 8));
        f16x8 kb0h = *(const f16x8*)&sKh[i0];
        f16x8 kb0l = *(const f16x8*)&sKl[i0];
        f16x8 kb1h = *(const f16x8*)&sKh[i1];
        f16x8 kb1l = *(const f16x8*)&sKl[i1];
        s0 = __builtin_amdgcn_mfma_f32_16x16x32_f16(qh[kk], kb0h, s0, 0, 0, 0);
        s0 = __builtin_amdgcn_mfma_f32_16x16x32_f16(qh[kk], kb0l, s0, 0, 0, 0);
        s0 = __builtin_amdgcn_mfma_f32_16x16x32_f16(ql[kk], kb0h, s0, 0, 0, 0);
        s1 = __builtin_amdgcn_mfma_f32_16x16x32_f16(qh[kk], kb1h, s1, 0, 0, 0);
        s1 = __builtin_amdgcn_mfma_f32_16x16x32_f16(qh[kk], kb1l, s1, 0, 0, 0);
        s1 = __builtin_amdgcn_mfma_f32_16x16x32_f16(ql[kk], kb1h, s1, 0, 0, 0);
      }
      const int qg = qt * 64 + wid * 16 + (lane >> 4) * 4;
      if (kt == ntw - 1) {
#pragma unroll
        for (int r = 0; r < 4; ++r) {
          int q = qg + r;
          int k0 = kt * 32 + l16, k1 = k0 + 16;
          s0[r] = (k0 <= q) ? s0[r] * scale : -1e30f;
          s1[r] = (k1 <= q) ? s1[r] * scale : -1e30f;
        }
      } else {
#pragma unroll
        for (int r = 0; r < 4; ++r) { s0[r] *= scale; s1[r] *= scale; }
      }
      float p0[4], p1[4], fr[4];
#pragma unroll
      for (int r = 0; r < 4; ++r) {
        float rm = fmaxf(s0[r], s1[r]);
        rm = fmaxf(rm, __shfl_xor(rm, 1));
        rm = fmaxf(rm, __shfl_xor(rm, 2));
        rm = fmaxf(rm, __shfl_xor(rm, 4));
        rm = fmaxf(rm, __shfl_xor(rm, 8));
        float mn = fmaxf(m_[r], rm);
        fr[r] = __expf(m_[r] - mn);
        m_[r] = mn;
        p0[r] = __expf(s0[r] - mn);
        p1[r] = __expf(s1[r] - mn);
        float rs = p0[r] + p1[r];
        rs += __shfl_xor(rs, 1);
        rs += __shfl_xor(rs, 2);
        rs += __shfl_xor(rs, 4);
        rs += __shfl_xor(rs, 8);
        l_[r] = l_[r] * fr[r] + rs;
      }
#pragma unroll
      for (int i = 0; i < 8; ++i)
#pragma unroll
        for (int r = 0; r < 4; ++r) of[i][r] *= fr[r];
#pragma unroll
      for (int r = 0; r < 4; ++r) {
        int q = (lane >> 4) * 4 + r;
        int swz = ((q >> 1) & 3) * 8;
        int c0 = l16, c1 = 16 + l16;
        _Float16 h0 = (_Float16)p0[r];
        _Float16 h1 = (_Float16)p1[r];
        sPh[wid * 512 + q * 32 + (c0 ^ swz)] = h0;
        sPl[wid * 512 + q * 32 + (c0 ^ swz)] = (_Float16)(p0[r] - (float)h0);
        sPh[wid * 512 + q * 32 + (c1 ^ swz)] = h1;
        sPl[wid * 512 + q * 32 + (c1 ^ swz)] = (_Float16)(p1[r] - (float)h1);
      }
      int pidxr = wid * 512 + l16 * 32 + ((lhi * 8) ^ (((l16 >> 1) & 3) * 8));
      f16x8 pah = *(const f16x8*)&sPh[pidxr];
      f16x8 pal = *(const f16x8*)&sPl[pidxr];
#pragma unroll
      for (int d16 = 0; d16 < 8; ++d16) {
        int d = d16 * 16 + l16;
        int vidx = d * 32 + ((lhi * 8) ^ (((d >> 1) & 3) * 8));
        f16x8 vbh = *(const f16x8*)&sVh[vidx];
        f16x8 vbl = *(const f16x8*)&sVl[vidx];
        f32x4 a = of[d16];
        a = __builtin_amdgcn_mfma_f32_16x16x32_f16(pah, vbh, a, 0, 0, 0);
        a = __builtin_amdgcn_mfma_f32_16x16x32_f16(pah, vbl, a, 0, 0, 0);
        a = __builtin_amdgcn_mfma_f32_16x16x32_f16(pal, vbh, a, 0, 0, 0);
        of[d16] = a;
      }
    }
  }
  float inv[4];
#pragma unroll
  for (int r = 0; r < 4; ++r) inv[r] = 1.f / l_[r];
  const int qg = qt * 64 + wid * 16 + (lane >> 4) * 4;
#pragma unroll
  for (int d16 = 0; d16 < 8; ++d16)
#pragma unroll
    for (int r = 0; r < 4; ++r) {
      float val = of[d16][r] * inv[r];
      size_t gi = qkbase + (size_t)(qg + r) * DMODEL + d16 * 16 + l16;
      O[gi] = val;
      _Float16 hh = (_Float16)val;
      Oh[gi] = hh;
      Ol[gi] = (_Float16)(val - (float)hh);
    }
}

// ---------------------------------------------------------------------------
extern "C" void kernel_launch(void* const* d_in, const int* in_sizes, int n_in,
                              void* d_out, int out_size, void* d_ws, size_t ws_size,
                              hipStream_t stream) {
  (void)in_sizes; (void)n_in; (void)out_size;
  const float* x        = (const float*)d_in[0];
  const float* Wr_in    = (const float*)d_in[2];
  const float* Wr_proc  = (const float*)d_in[3];
  const float* Wr_out   = (const float*)d_in[4];
  const float* WrO_in   = (const float*)d_in[5];
  const float* WrO_proc = (const float*)d_in[6];
  const float* WrO_out  = (const float*)d_in[7];
  const float* Wq_in    = (const float*)d_in[8];
  const float* vq       = (const float*)d_in[9];
  const float* Wq_out   = (const float*)d_in[10];
  const float* Wk_in    = (const float*)d_in[11];
  const float* vk       = (const float*)d_in[12];
  const float* Wk_out   = (const float*)d_in[13];
  const float* Wv_in    = (const float*)d_in[14];
  const float* vv       = (const float*)d_in[15];
  const float* Wv_out   = (const float*)d_in[16];
  const float* Wo_in    = (const float*)d_in[17];
  const float* vo       = (const float*)d_in[18];
  const float* Wo_out   = (const float*)d_in[19];

  char* wsbase = (char*)d_ws;
  size_t off = 0;
  auto carve = [&](size_t bytes) -> void* {
    void* r = wsbase + off;
    off = (off + bytes + 255) & ~(size_t)255;
    return r;
  };
  const size_t WBYTES = (size_t)KDIM * DMODEL * 2;     // 16.78 MB (B plane)
  const size_t PBYTES = (size_t)TOK * DMODEL * 2;      // 8.39 MB (A plane)
  const size_t HBYTES = (size_t)TOK * DMODEL * 4;      // 16.78 MB (fp32)
  _Float16* WTh = (_Float16*)carve(WBYTES);
  _Float16* WTl = (_Float16*)carve(WBYTES);
  _Float16* Xh  = (_Float16*)carve(PBYTES);
  _Float16* Xl  = (_Float16*)carve(PBYTES);
  _Float16* Hh  = (_Float16*)carve(PBYTES);
  _Float16* Hl  = (_Float16*)carve(PBYTES);
  float* c0 = (float*)carve(HBYTES);
  float* c1 = (float*)carve(HBYTES);
  float* r1 = (float*)carve(HBYTES);
  float* r2 = (float*)carve(HBYTES);
  float* iw1 = (float*)carve((size_t)TOK * 8 * 4);
  float* ow1 = (float*)carve((size_t)TOK * 8 * 4);
  float* iw2 = (float*)carve((size_t)TOK * 8 * 4);
  float* ow2 = (float*)carve((size_t)TOK * 8 * 4);
  int* pi1 = (int*)carve((size_t)TOK * 3 * 4);
  int* pi2 = (int*)carve((size_t)TOK * 3 * 4);

  if (off > ws_size) {   // diagnosable failure instead of OOB abort
    hipMemsetAsync(d_out, 0, (size_t)out_size * 4, stream);
    return;
  }

  // Aliases (lifetime-disjoint):
  float* Vt = (float*)WTh;                 // 16.78 MB, lives attn-only
  _Float16* Oh = (_Float16*)r1;            // O planes overwrite Q (block-
  _Float16* Ol = Oh + (size_t)TOK * DMODEL;//  exclusive rectangles in attn)

  const dim3 blk(256);
  const dim3 tgrid(KDIM / 64, DMODEL / 64);        // (128, 16)
  const dim3 ggrid(TOK / 128, DMODEL / 128, 2);    // (32, 8, 2) split-K
  const dim3 rgrid(TOK * DMODEL / (256 * 4));      // 4096
  const dim3 vgrid(S_LEN / 64, 2, 16);
  const dim3 agrid(S_LEN / 64, 16);

  split_kernel<<<rgrid, blk, 0, stream>>>(x, Xh, Xl);
  router_kernel<<<TOK, blk, 0, stream>>>(x, Wr_in, Wr_proc, Wr_out, iw1, ow1, pi1);

  // Q circuit
  transpose_split<<<tgrid, blk, 0, stream>>>(Wq_in, WTh, WTl);
  gemm_planes<<<ggrid, blk, 0, stream>>>(Xh, Xl, iw1, WTh, WTl, c0, c1);
  reflect_kernel<<<TOK, blk, 0, stream>>>(c0, c1, pi1, vq, Hh, Hl);
  transpose_split<<<tgrid, blk, 0, stream>>>(Wq_out, WTh, WTl);
  gemm_planes<<<ggrid, blk, 0, stream>>>(Hh, Hl, ow1, WTh, WTl, c0, c1);
  reduce_add<<<rgrid, blk, 0, stream>>>(c0, c1, r1);               // Q -> r1

  // K circuit
  transpose_split<<<tgrid, blk, 0, stream>>>(Wk_in, WTh, WTl);
  gemm_planes<<<ggrid, blk, 0, stream>>>(Xh, Xl, iw1, WTh, WTl, c0, c1);
  reflect_kernel<<<TOK, blk, 0, stream>>>(c0, c1, pi1, vk, Hh, Hl);
  transpose_split<<<tgrid, blk, 0, stream>>>(Wk_out, WTh, WTl);
  gemm_planes<<<ggrid, blk, 0, stream>>>(Hh, Hl, ow1, WTh, WTl, c0, c1);
  reduce_add<<<rgrid, blk, 0, stream>>>(c0, c1, r2);               // K -> r2

  // V circuit
  transpose_split<<<tgrid, blk, 0, stream>>>(Wv_in, WTh, WTl);
  gemm_planes<<<ggrid, blk, 0, stream>>>(Xh, Xl, iw1, WTh, WTl, c0, c1);
  reflect_kernel<<<TOK, blk, 0, stream>>>(c0, c1, pi1, vv, Hh, Hl);
  transpose_split<<<tgrid, blk, 0, stream>>>(Wv_out, WTh, WTl);
  gemm_planes<<<ggrid, blk, 0, stream>>>(Hh, Hl, ow1, WTh, WTl, c0, c1);
  vtrans_kernel<<<vgrid, blk, 0, stream>>>(c0, c1, Vt);            // Vt -> WTh alias

  // attention: Q=r1 K=r2 Vt -> O=c0 (+ planes Oh/Ol aliased on r1)
  attn_kernel<<<agrid, blk, 0, stream>>>(r1, r2, Vt, c0, Oh, Ol);

  // router 2 + final circuit
  router_kernel<<<TOK, blk, 0, stream>>>(c0, WrO_in, WrO_proc, WrO_out, iw2, ow2, pi2);
  transpose_split<<<tgrid, blk, 0, stream>>>(Wo_in, WTh, WTl);
  gemm_planes<<<ggrid, blk, 0, stream>>>(Oh, Ol, iw2, WTh, WTl, c1, r2);
  reflect_kernel<<<TOK, blk, 0, stream>>>(c1, r2, pi2, vo, Hh, Hl);
  transpose_split<<<tgrid, blk, 0, stream>>>(Wo_out, WTh, WTl);
  gemm_planes<<<ggrid, blk, 0, stream>>>(Hh, Hl, ow2, WTh, WTl, c0, c1);
  reduce_add<<<rgrid, blk, 0, stream>>>(c0, c1, (float*)d_out);
}